// Round 1
// baseline (190.468 us; speedup 1.0000x reference)
//
#include <hip/hip_runtime.h>

#define HW (128*128)
#define CHW (64*HW)

// ---------------- setup: fold the conv chains into 64x64 matrices ----------------
__global__ __launch_bounds__(256) void setup_kernel(
    const float* __restrict__ alpha,
    const float* __restrict__ q_dw, const float* __restrict__ q_pw, const float* __restrict__ q_pb,
    const float* __restrict__ k_dw, const float* __restrict__ k_pw,
    const float* __restrict__ v_dw, const float* __restrict__ v_pw, const float* __restrict__ v_pb,
    const float* __restrict__ o_dw, const float* __restrict__ o_pw, const float* __restrict__ o_pb,
    float* __restrict__ Mqk, float* __restrict__ qkb,
    float* __restrict__ Mov, float* __restrict__ Moq, float* __restrict__ bout)
{
  int bb = blockIdx.x;
  int tid = threadIdx.x;
  float a = alpha[0];
  if (bb < 16) {
    int e = bb*256 + tid; int c = e >> 6, c2 = e & 63;
    float s = 0.f;
    for (int o = 0; o < 64; ++o) s += k_pw[o*64+c]*q_pw[o*64+c2];
    Mqk[e] = k_dw[c]*q_dw[c2]*s;
  } else if (bb < 32) {
    int e = (bb-16)*256 + tid; int co = e >> 6, c2 = e & 63;
    float s = 0.f;
    for (int h = 0; h < 64; ++h) s += o_pw[co*64+h]*o_dw[h]*v_pw[h*64+c2];
    Mov[e] = a*v_dw[c2]*s;
  } else if (bb < 48) {
    int e = (bb-32)*256 + tid; int co = e >> 6, c2 = e & 63;
    float s = 0.f;
    for (int h = 0; h < 64; ++h) s += o_pw[co*64+h]*o_dw[h]*q_pw[h*64+c2];
    Moq[e] = q_dw[c2]*s;
  } else {
    if (tid < 64) {
      float s = 0.f;
      for (int o = 0; o < 64; ++o) s += k_pw[o*64+tid]*q_pb[o];
      qkb[tid] = k_dw[tid]*s;
      float s2 = 0.f;
      for (int h = 0; h < 64; ++h) s2 += o_pw[tid*64+h]*o_dw[h]*(a*v_pb[h]+q_pb[h]);
      bout[tid] = o_pb[tid] + s2;
    }
  }
}

// ---------------- transpose x (B,C,H,W) -> xt (B,H,W,C) for channel-contiguous gathers --
__global__ __launch_bounds__(256) void transpose_kernel(const float* __restrict__ x,
                                                        float* __restrict__ xt)
{
  __shared__ float t[64][65];
  int blk = blockIdx.x;
  int b = blk >> 8; int y = (blk >> 1) & 127; int x0 = (blk & 1) << 6;
  int tid = threadIdx.x;
  int p = tid & 63, cq = tid >> 6;
  const float* xb = x + b*CHW + y*128 + x0;
  #pragma unroll
  for (int i = 0; i < 16; ++i) {
    int c = i*4 + cq;
    t[c][p] = xb[c*HW + p];
  }
  __syncthreads();
  int cc = tid & 63, pq = tid >> 6;
  float* xtb = xt + (size_t)(b*HW + y*128 + x0)*64;
  #pragma unroll
  for (int i = 0; i < 16; ++i) {
    int pp = i*4 + pq;
    xtb[pp*64 + cc] = t[cc][pp];
  }
}

// ---------------- bilinear sample address/weight setup (matches reference arithmetic) ---
__device__ __forceinline__ void samp_setup(
    int k, int p, float fx, float fy,
    const float (*offs)[64],
    const float* __restrict__ xtb,
    const float*& p00, const float*& p01, const float*& p10, const float*& p11,
    float& w00, float& w01, float& w10, float& w11)
{
  float dx = offs[k][p];
  float dy = offs[9+k][p];
  float gx = 2.0f*(fx + dx)/127.0f - 1.0f;
  float gy = 2.0f*(fy + dy)/127.0f - 1.0f;
  float ix = ((gx + 1.0f)*128.0f - 1.0f)*0.5f;
  float iy = ((gy + 1.0f)*128.0f - 1.0f)*0.5f;
  float x0f = floorf(ix), y0f = floorf(iy);
  float wx = ix - x0f, wy = iy - y0f;
  int xi = (int)x0f, yi = (int)y0f;
  bool vx0 = (xi >= 0) && (xi < 128);
  bool vx1 = (xi >= -1) && (xi < 127);
  bool vy0 = (yi >= 0) && (yi < 128);
  bool vy1 = (yi >= -1) && (yi < 127);
  w00 = (1.f-wy)*(1.f-wx)*((vy0&&vx0)?1.f:0.f);
  w01 = (1.f-wy)*wx      *((vy0&&vx1)?1.f:0.f);
  w10 = wy*(1.f-wx)      *((vy1&&vx0)?1.f:0.f);
  w11 = wy*wx            *((vy1&&vx1)?1.f:0.f);
  int xc0 = min(max(xi,0),127), xc1 = min(max(xi+1,0),127);
  int yc0 = min(max(yi,0),127), yc1 = min(max(yi+1,0),127);
  p00 = xtb + (yc0*128 + xc0)*64;
  p01 = xtb + (yc0*128 + xc1)*64;
  p10 = xtb + (yc1*128 + xc0)*64;
  p11 = xtb + (yc1*128 + xc1)*64;
}

// ---------------- fused main kernel: 64 pixels per block, 256 threads -------------------
__global__ __launch_bounds__(256) void dam_kernel(
  const float* __restrict__ x, const float* __restrict__ xt,
  const float* __restrict__ offw, const float* __restrict__ offb,
  const float* __restrict__ Mqk, const float* __restrict__ qkb,
  const float* __restrict__ Mov, const float* __restrict__ Moq, const float* __restrict__ bout,
  float* __restrict__ out)
{
  __shared__ float xs[64][65];     // x tile   [c][p]
  __shared__ float qs[64][65];     // qk, later S  [c][p]
  __shared__ float offs[18][64];   // offsets  [j][p]
  __shared__ float part[4][9][64]; // score partials [cq][k][p]
  __shared__ float sc[9][64];      // scores -> attn [k][p]

  int blk = blockIdx.x;
  int b = blk >> 8; int y = (blk >> 1) & 127; int x0 = (blk & 1) << 6;
  int tid = threadIdx.x;
  int p = tid & 63;
  int cq = tid >> 6;
  int wv = __builtin_amdgcn_readfirstlane(cq);

  // P1: stage x tile into LDS (coalesced per-channel row reads)
  const float* xb = x + b*CHW + y*128 + x0;
  #pragma unroll
  for (int i = 0; i < 16; ++i) {
    int c = i*4 + cq;
    xs[c][p] = xb[c*HW + p];
  }
  __syncthreads();

  // P2a: qk = Mqk @ x_pix + qkb   (wave wv computes output rows 16wv..16wv+15)
  {
    float acc[16];
    #pragma unroll
    for (int oi = 0; oi < 16; ++oi) acc[oi] = qkb[wv*16+oi];
    for (int c = 0; c < 64; ++c) {
      float xv = xs[c][p];
      #pragma unroll
      for (int oi = 0; oi < 16; ++oi)
        acc[oi] += Mqk[(wv*16+oi)*64 + c] * xv;
    }
    #pragma unroll
    for (int oi = 0; oi < 16; ++oi) qs[wv*16+oi][p] = acc[oi];
  }
  // P2b: offsets = offw @ x_pix + offb  (18 rows split 5/5/5/3 across waves)
  {
    float acc[5];
    int jb = wv*5;
    #pragma unroll
    for (int r = 0; r < 5; ++r) acc[r] = (jb+r < 18) ? offb[jb+r] : 0.f;
    for (int c = 0; c < 64; ++c) {
      float xv = xs[c][p];
      #pragma unroll
      for (int r = 0; r < 5; ++r)
        if (jb + r < 18) acc[r] += offw[(jb+r)*64 + c] * xv;
    }
    #pragma unroll
    for (int r = 0; r < 5; ++r)
      if (jb + r < 18) offs[jb+r][p] = acc[r];
  }
  __syncthreads();

  const float* xtb = xt + (size_t)b*HW*64 + cq*16;
  float fx = (float)(x0 + p);
  float fy = (float)y;

  // P3: pass-1 sampling -> per-wave partial scores (16 channels each)
  #pragma unroll 1
  for (int k = 0; k < 9; ++k) {
    const float *p00, *p01, *p10, *p11;
    float w00, w01, w10, w11;
    samp_setup(k, p, fx, fy, offs, xtb, p00, p01, p10, p11, w00, w01, w10, w11);
    float acc = 0.f;
    #pragma unroll
    for (int i = 0; i < 4; ++i) {
      float4 a00 = *(const float4*)(p00 + i*4);
      float4 a01 = *(const float4*)(p01 + i*4);
      float4 a10 = *(const float4*)(p10 + i*4);
      float4 a11 = *(const float4*)(p11 + i*4);
      int c = cq*16 + i*4;
      acc += (w00*a00.x + w01*a01.x + w10*a10.x + w11*a11.x) * qs[c+0][p];
      acc += (w00*a00.y + w01*a01.y + w10*a10.y + w11*a11.y) * qs[c+1][p];
      acc += (w00*a00.z + w01*a01.z + w10*a10.z + w11*a11.z) * qs[c+2][p];
      acc += (w00*a00.w + w01*a01.w + w10*a10.w + w11*a11.w) * qs[c+3][p];
    }
    part[cq][k][p] = acc;
  }
  __syncthreads();

  // P4: reduce partials + softmax over k (9)
  for (int e = tid; e < 9*64; e += 256) {
    int k = e >> 6, pp = e & 63;
    sc[k][pp] = part[0][k][pp] + part[1][k][pp] + part[2][k][pp] + part[3][k][pp];
  }
  __syncthreads();
  if (tid < 64) {
    float m = sc[0][tid];
    #pragma unroll
    for (int k = 1; k < 9; ++k) m = fmaxf(m, sc[k][tid]);
    float s = 0.f;
    #pragma unroll
    for (int k = 0; k < 9; ++k) { float e2 = __expf(sc[k][tid]-m); s += e2; sc[k][tid] = e2; }
    float inv = 1.f/s;
    #pragma unroll
    for (int k = 0; k < 9; ++k) sc[k][tid] *= inv;
  }
  __syncthreads();

  // P5: pass-2 sampling -> S = sum_k attn_k * s_k (16 channels per thread, in regs)
  float S[16];
  #pragma unroll
  for (int i = 0; i < 16; ++i) S[i] = 0.f;
  #pragma unroll 1
  for (int k = 0; k < 9; ++k) {
    const float *p00, *p01, *p10, *p11;
    float w00, w01, w10, w11;
    samp_setup(k, p, fx, fy, offs, xtb, p00, p01, p10, p11, w00, w01, w10, w11);
    float ak = sc[k][p];
    #pragma unroll
    for (int i = 0; i < 4; ++i) {
      float4 a00 = *(const float4*)(p00 + i*4);
      float4 a01 = *(const float4*)(p01 + i*4);
      float4 a10 = *(const float4*)(p10 + i*4);
      float4 a11 = *(const float4*)(p11 + i*4);
      S[i*4+0] += ak*(w00*a00.x + w01*a01.x + w10*a10.x + w11*a11.x);
      S[i*4+1] += ak*(w00*a00.y + w01*a01.y + w10*a10.y + w11*a11.y);
      S[i*4+2] += ak*(w00*a00.z + w01*a01.z + w10*a10.z + w11*a11.z);
      S[i*4+3] += ak*(w00*a00.w + w01*a01.w + w10*a10.w + w11*a11.w);
    }
  }
  // qs reads from P3 are sealed behind the P4 barriers -> safe to overwrite with S
  #pragma unroll
  for (int i = 0; i < 16; ++i) qs[cq*16+i][p] = S[i];
  __syncthreads();

  // P6: result = Mov @ S + Moq @ x_pix + bout ; coalesced store
  {
    float acc[16];
    #pragma unroll
    for (int oi = 0; oi < 16; ++oi) acc[oi] = bout[wv*16+oi];
    for (int c = 0; c < 64; ++c) {
      float sv = qs[c][p];
      float xv = xs[c][p];
      #pragma unroll
      for (int oi = 0; oi < 16; ++oi) {
        int o = wv*16+oi;
        acc[oi] += Mov[o*64+c]*sv + Moq[o*64+c]*xv;
      }
    }
    float* ob = out + b*CHW + y*128 + x0;
    #pragma unroll
    for (int oi = 0; oi < 16; ++oi) {
      int o = wv*16+oi;
      ob[o*HW + p] = acc[oi];
    }
  }
}

extern "C" void kernel_launch(void* const* d_in, const int* in_sizes, int n_in,
                              void* d_out, int out_size, void* d_ws, size_t ws_size,
                              hipStream_t stream)
{
  const float* x    = (const float*)d_in[0];
  const float* alpha= (const float*)d_in[1];
  const float* offw = (const float*)d_in[2];
  const float* offb = (const float*)d_in[3];
  const float* q_dw = (const float*)d_in[4];
  const float* q_pw = (const float*)d_in[5];
  const float* q_pb = (const float*)d_in[6];
  const float* k_dw = (const float*)d_in[7];
  const float* k_pw = (const float*)d_in[8];
  const float* v_dw = (const float*)d_in[10];
  const float* v_pw = (const float*)d_in[11];
  const float* v_pb = (const float*)d_in[12];
  const float* o_dw = (const float*)d_in[13];
  const float* o_pw = (const float*)d_in[14];
  const float* o_pb = (const float*)d_in[15];
  float* out = (float*)d_out;

  float* ws  = (float*)d_ws;
  float* xt  = ws;                       // 4*128*128*64 floats = 16 MB
  float* Mqk = ws + (size_t)4*HW*64;
  float* Mov = Mqk + 4096;
  float* Moq = Mov + 4096;
  float* qkb = Moq + 4096;
  float* bout= qkb + 64;

  setup_kernel<<<49, 256, 0, stream>>>(alpha, q_dw, q_pw, q_pb, k_dw, k_pw,
                                       v_dw, v_pw, v_pb, o_dw, o_pw, o_pb,
                                       Mqk, qkb, Mov, Moq, bout);
  transpose_kernel<<<1024, 256, 0, stream>>>(x, xt);
  dam_kernel<<<1024, 256, 0, stream>>>(x, xt, offw, offb, Mqk, qkb, Mov, Moq, bout, out);
}

// Round 2
// 115.092 us; speedup vs baseline: 1.6549x; 1.6549x over previous
//
#include <hip/hip_runtime.h>
#include <hip/hip_fp16.h>

#define HW (128*128)
#define CHW (64*HW)

union FH { float f; __half2 h; };
__device__ __forceinline__ __half2 f2h2(float v) { FH u; u.f = v; return u.h; }

// ---------------- setup: fold the conv chains into 64x64 matrices ----------------
__global__ __launch_bounds__(256) void setup_kernel(
    const float* __restrict__ alpha,
    const float* __restrict__ q_dw, const float* __restrict__ q_pw, const float* __restrict__ q_pb,
    const float* __restrict__ k_dw, const float* __restrict__ k_pw,
    const float* __restrict__ v_dw, const float* __restrict__ v_pw, const float* __restrict__ v_pb,
    const float* __restrict__ o_dw, const float* __restrict__ o_pw, const float* __restrict__ o_pb,
    float* __restrict__ Mqk, float* __restrict__ qkb,
    float* __restrict__ Mov, float* __restrict__ Moq, float* __restrict__ bout)
{
  int bb = blockIdx.x;
  int tid = threadIdx.x;
  float a = alpha[0];
  if (bb < 16) {
    int e = bb*256 + tid; int c = e >> 6, c2 = e & 63;
    float s = 0.f;
    for (int o = 0; o < 64; ++o) s += k_pw[o*64+c]*q_pw[o*64+c2];
    Mqk[e] = k_dw[c]*q_dw[c2]*s;
  } else if (bb < 32) {
    int e = (bb-16)*256 + tid; int co = e >> 6, c2 = e & 63;
    float s = 0.f;
    for (int h = 0; h < 64; ++h) s += o_pw[co*64+h]*o_dw[h]*v_pw[h*64+c2];
    Mov[e] = a*v_dw[c2]*s;
  } else if (bb < 48) {
    int e = (bb-32)*256 + tid; int co = e >> 6, c2 = e & 63;
    float s = 0.f;
    for (int h = 0; h < 64; ++h) s += o_pw[co*64+h]*o_dw[h]*q_pw[h*64+c2];
    Moq[e] = q_dw[c2]*s;
  } else {
    if (tid < 64) {
      float s = 0.f;
      for (int o = 0; o < 64; ++o) s += k_pw[o*64+tid]*q_pb[o];
      qkb[tid] = k_dw[tid]*s;
      float s2 = 0.f;
      for (int h = 0; h < 64; ++h) s2 += o_pw[tid*64+h]*o_dw[h]*(a*v_pb[h]+q_pb[h]);
      bout[tid] = o_pb[tid] + s2;
    }
  }
}

// ---------------- transpose x (B,C,H,W) -> xt (B,H,W,C) fp16, channel-contiguous --------
__global__ __launch_bounds__(256) void transpose_kernel(const float* __restrict__ x,
                                                        __half* __restrict__ xt)
{
  __shared__ float t[64][65];
  int i0 = blockIdx.x;
  int blk = (i0 & 7)*128 + (i0 >> 3);      // same XCD swizzle as dam_kernel
  int b = blk >> 8; int y = (blk >> 1) & 127; int x0 = (blk & 1) << 6;
  int tid = threadIdx.x;
  int p = tid & 63, cq = tid >> 6;
  const float* xb = x + b*CHW + y*128 + x0;
  #pragma unroll
  for (int i = 0; i < 16; ++i) {
    int c = i*4 + cq;
    t[c][p] = xb[c*HW + p];
  }
  __syncthreads();
  int cpair = tid & 31, pq = tid >> 5;     // pq in 0..7
  __half2* xtb = (__half2*)(xt + (size_t)(b*HW + y*128 + x0)*64);
  #pragma unroll
  for (int i = 0; i < 8; ++i) {
    int pp = i*8 + pq;
    xtb[pp*32 + cpair] = __floats2half2_rn(t[cpair*2][pp], t[cpair*2+1][pp]);
  }
}

// ---------------- bilinear sample address/weight setup (matches reference arithmetic) ---
__device__ __forceinline__ void samp_setup(
    int k, int p, float fx, float fy,
    const float (*offs)[64],
    const __half* __restrict__ xtb,
    const __half*& p00, const __half*& p01, const __half*& p10, const __half*& p11,
    float& w00, float& w01, float& w10, float& w11)
{
  float dx = offs[k][p];
  float dy = offs[9+k][p];
  float gx = 2.0f*(fx + dx)/127.0f - 1.0f;
  float gy = 2.0f*(fy + dy)/127.0f - 1.0f;
  float ix = ((gx + 1.0f)*128.0f - 1.0f)*0.5f;
  float iy = ((gy + 1.0f)*128.0f - 1.0f)*0.5f;
  float x0f = floorf(ix), y0f = floorf(iy);
  float wx = ix - x0f, wy = iy - y0f;
  int xi = (int)x0f, yi = (int)y0f;
  bool vx0 = (xi >= 0) && (xi < 128);
  bool vx1 = (xi >= -1) && (xi < 127);
  bool vy0 = (yi >= 0) && (yi < 128);
  bool vy1 = (yi >= -1) && (yi < 127);
  w00 = (1.f-wy)*(1.f-wx)*((vy0&&vx0)?1.f:0.f);
  w01 = (1.f-wy)*wx      *((vy0&&vx1)?1.f:0.f);
  w10 = wy*(1.f-wx)      *((vy1&&vx0)?1.f:0.f);
  w11 = wy*wx            *((vy1&&vx1)?1.f:0.f);
  int xc0 = min(max(xi,0),127), xc1 = min(max(xi+1,0),127);
  int yc0 = min(max(yi,0),127), yc1 = min(max(yi+1,0),127);
  p00 = xtb + (yc0*128 + xc0)*64;
  p01 = xtb + (yc0*128 + xc1)*64;
  p10 = xtb + (yc1*128 + xc0)*64;
  p11 = xtb + (yc1*128 + xc1)*64;
}

// 4-corner lerp of 8 channels (one float4 = 8 halves per corner), packed fp16
__device__ __forceinline__ void mix8(const float4& a, const float4& b, const float4& c, const float4& d,
                                     __half2 w0, __half2 w1, __half2 w2, __half2 w3,
                                     __half2* v)
{
  v[0] = __hfma2(w3, f2h2(d.x), __hfma2(w2, f2h2(c.x), __hfma2(w1, f2h2(b.x), __hmul2(w0, f2h2(a.x)))));
  v[1] = __hfma2(w3, f2h2(d.y), __hfma2(w2, f2h2(c.y), __hfma2(w1, f2h2(b.y), __hmul2(w0, f2h2(a.y)))));
  v[2] = __hfma2(w3, f2h2(d.z), __hfma2(w2, f2h2(c.z), __hfma2(w1, f2h2(b.z), __hmul2(w0, f2h2(a.z)))));
  v[3] = __hfma2(w3, f2h2(d.w), __hfma2(w2, f2h2(c.w), __hfma2(w1, f2h2(b.w), __hmul2(w0, f2h2(a.w)))));
}

// ---------------- fused main kernel: 64 pixels per block, 256 threads -------------------
__global__ __launch_bounds__(256) void dam_kernel(
  const float* __restrict__ x, const __half* __restrict__ xt,
  const float* __restrict__ offw, const float* __restrict__ offb,
  const float* __restrict__ Mqk, const float* __restrict__ qkb,
  const float* __restrict__ Mov, const float* __restrict__ Moq, const float* __restrict__ bout,
  float* __restrict__ out)
{
  __shared__ __half xs[64][66];    // x tile   [c][p] fp16
  __shared__ __half qs[64][66];    // S        [c][p] fp16 (written in pass 2)
  __shared__ float offs[18][64];   // offsets  [j][p]
  __shared__ float part[4][9][64]; // score partials [cq][k][p]; part[0] reused as sc/attn

  int i0 = blockIdx.x;
  int blk = (i0 & 7)*128 + (i0 >> 3);      // XCD swizzle: 64 consecutive rows per XCD
  int b = blk >> 8; int y = (blk >> 1) & 127; int x0 = (blk & 1) << 6;
  int tid = threadIdx.x;
  int p = tid & 63;
  int cq = tid >> 6;
  int wv = __builtin_amdgcn_readfirstlane(cq);

  // P1: stage x tile into LDS as fp16 (coalesced per-channel row reads)
  const float* xb = x + b*CHW + y*128 + x0;
  #pragma unroll
  for (int i = 0; i < 16; ++i) {
    int c = i*4 + cq;
    xs[c][p] = __float2half(xb[c*HW + p]);
  }
  __syncthreads();

  // P2a: qk slice = (Mqk @ x_pix + qkb)[wv*16 .. wv*16+16) kept in REGISTERS.
  // Wave cq's scoring needs exactly channels [cq*16, cq*16+16) of qk for its pixel p.
  float qkr[16];
  {
    #pragma unroll
    for (int oi = 0; oi < 16; ++oi) qkr[oi] = qkb[wv*16+oi];
    for (int c = 0; c < 64; ++c) {
      float xv = __half2float(xs[c][p]);
      #pragma unroll
      for (int oi = 0; oi < 16; ++oi)
        qkr[oi] += Mqk[(wv*16+oi)*64 + c] * xv;
    }
  }
  // P2b: offsets = offw @ x_pix + offb  (18 rows split 5/5/5/3 across waves)
  {
    float acc[5];
    int jb = wv*5;
    #pragma unroll
    for (int r = 0; r < 5; ++r) acc[r] = (jb+r < 18) ? offb[jb+r] : 0.f;
    for (int c = 0; c < 64; ++c) {
      float xv = __half2float(xs[c][p]);
      #pragma unroll
      for (int r = 0; r < 5; ++r)
        if (jb + r < 18) acc[r] += offw[(jb+r)*64 + c] * xv;
    }
    #pragma unroll
    for (int r = 0; r < 5; ++r)
      if (jb + r < 18) offs[jb+r][p] = acc[r];
  }
  __syncthreads();

  const __half* xtb = xt + (size_t)b*HW*64 + cq*16;
  float fx = (float)(x0 + p);
  float fy = (float)y;

  // P3: pass-1 sampling -> per-wave partial scores (16 channels each)
  #pragma unroll 1
  for (int k = 0; k < 9; ++k) {
    const __half *p00, *p01, *p10, *p11;
    float w00, w01, w10, w11;
    samp_setup(k, p, fx, fy, offs, xtb, p00, p01, p10, p11, w00, w01, w10, w11);
    __half2 wh0 = __float2half2_rn(w00), wh1 = __float2half2_rn(w01);
    __half2 wh2 = __float2half2_rn(w10), wh3 = __float2half2_rn(w11);
    const float4* q00 = (const float4*)p00; const float4* q01 = (const float4*)p01;
    const float4* q10 = (const float4*)p10; const float4* q11 = (const float4*)p11;
    float4 A0 = q00[0], B0 = q01[0], C0 = q10[0], D0 = q11[0];
    float4 A1 = q00[1], B1 = q01[1], C1 = q10[1], D1 = q11[1];
    __half2 v[8];
    mix8(A0,B0,C0,D0, wh0,wh1,wh2,wh3, v);
    mix8(A1,B1,C1,D1, wh0,wh1,wh2,wh3, v+4);
    float s = 0.f;
    #pragma unroll
    for (int j = 0; j < 8; ++j)
      s += __low2float(v[j])*qkr[2*j] + __high2float(v[j])*qkr[2*j+1];
    part[cq][k][p] = s;
  }
  __syncthreads();

  // P4: reduce partials in place (into part[0]) + softmax over k
  float (*sc)[64] = part[0];
  for (int e = tid; e < 9*64; e += 256) {
    int k = e >> 6, pp = e & 63;
    sc[k][pp] = part[0][k][pp] + part[1][k][pp] + part[2][k][pp] + part[3][k][pp];
  }
  __syncthreads();
  if (tid < 64) {
    float m = sc[0][tid];
    #pragma unroll
    for (int k = 1; k < 9; ++k) m = fmaxf(m, sc[k][tid]);
    float s = 0.f;
    #pragma unroll
    for (int k = 0; k < 9; ++k) { float e2 = __expf(sc[k][tid]-m); s += e2; sc[k][tid] = e2; }
    float inv = 1.f/s;
    #pragma unroll
    for (int k = 0; k < 9; ++k) sc[k][tid] *= inv;
  }
  __syncthreads();

  // P5: pass-2 sampling -> S = sum_k attn_k * s_k (16 channels per thread, packed fp16)
  __half2 S2[8];
  #pragma unroll
  for (int j = 0; j < 8; ++j) S2[j] = __float2half2_rn(0.f);
  #pragma unroll 1
  for (int k = 0; k < 9; ++k) {
    const __half *p00, *p01, *p10, *p11;
    float w00, w01, w10, w11;
    samp_setup(k, p, fx, fy, offs, xtb, p00, p01, p10, p11, w00, w01, w10, w11);
    __half2 wh0 = __float2half2_rn(w00), wh1 = __float2half2_rn(w01);
    __half2 wh2 = __float2half2_rn(w10), wh3 = __float2half2_rn(w11);
    const float4* q00 = (const float4*)p00; const float4* q01 = (const float4*)p01;
    const float4* q10 = (const float4*)p10; const float4* q11 = (const float4*)p11;
    float4 A0 = q00[0], B0 = q01[0], C0 = q10[0], D0 = q11[0];
    float4 A1 = q00[1], B1 = q01[1], C1 = q10[1], D1 = q11[1];
    __half2 v[8];
    mix8(A0,B0,C0,D0, wh0,wh1,wh2,wh3, v);
    mix8(A1,B1,C1,D1, wh0,wh1,wh2,wh3, v+4);
    __half2 akh = __float2half2_rn(sc[k][p]);
    #pragma unroll
    for (int j = 0; j < 8; ++j) S2[j] = __hfma2(akh, v[j], S2[j]);
  }
  // write S channel slice to LDS for the output matvec
  #pragma unroll
  for (int j = 0; j < 8; ++j) {
    qs[cq*16 + 2*j    ][p] = __low2half(S2[j]);
    qs[cq*16 + 2*j + 1][p] = __high2half(S2[j]);
  }
  __syncthreads();

  // P6: result = Mov @ S + Moq @ x_pix + bout ; coalesced store
  {
    float acc[16];
    #pragma unroll
    for (int oi = 0; oi < 16; ++oi) acc[oi] = bout[wv*16+oi];
    for (int c = 0; c < 64; ++c) {
      float sv = __half2float(qs[c][p]);
      float xv = __half2float(xs[c][p]);
      #pragma unroll
      for (int oi = 0; oi < 16; ++oi) {
        int o = wv*16+oi;
        acc[oi] += Mov[o*64+c]*sv + Moq[o*64+c]*xv;
      }
    }
    float* ob = out + b*CHW + y*128 + x0;
    #pragma unroll
    for (int oi = 0; oi < 16; ++oi) {
      int o = wv*16+oi;
      ob[o*HW + p] = acc[oi];
    }
  }
}

extern "C" void kernel_launch(void* const* d_in, const int* in_sizes, int n_in,
                              void* d_out, int out_size, void* d_ws, size_t ws_size,
                              hipStream_t stream)
{
  const float* x    = (const float*)d_in[0];
  const float* alpha= (const float*)d_in[1];
  const float* offw = (const float*)d_in[2];
  const float* offb = (const float*)d_in[3];
  const float* q_dw = (const float*)d_in[4];
  const float* q_pw = (const float*)d_in[5];
  const float* q_pb = (const float*)d_in[6];
  const float* k_dw = (const float*)d_in[7];
  const float* k_pw = (const float*)d_in[8];
  const float* v_dw = (const float*)d_in[10];
  const float* v_pw = (const float*)d_in[11];
  const float* v_pb = (const float*)d_in[12];
  const float* o_dw = (const float*)d_in[13];
  const float* o_pw = (const float*)d_in[14];
  const float* o_pb = (const float*)d_in[15];
  float* out = (float*)d_out;

  char* ws   = (char*)d_ws;
  __half* xt = (__half*)ws;                          // 4*128*128*64 halves = 8.4 MB
  float* Mqk = (float*)(ws + (size_t)4*HW*64*sizeof(__half));
  float* Mov = Mqk + 4096;
  float* Moq = Mov + 4096;
  float* qkb = Moq + 4096;
  float* bout= qkb + 64;

  setup_kernel<<<49, 256, 0, stream>>>(alpha, q_dw, q_pw, q_pb, k_dw, k_pw,
                                       v_dw, v_pw, v_pb, o_dw, o_pw, o_pb,
                                       Mqk, qkb, Mov, Moq, bout);
  transpose_kernel<<<1024, 256, 0, stream>>>(x, xt);
  dam_kernel<<<1024, 256, 0, stream>>>(x, xt, offw, offb, Mqk, qkb, Mov, Moq, bout, out);
}

// Round 4
// 72.466 us; speedup vs baseline: 2.6284x; 1.5882x over previous
//
#include <hip/hip_runtime.h>

#define HW (128*128)
#define CHW (64*HW)

typedef _Float16 h2 __attribute__((ext_vector_type(2)));
typedef _Float16 h8 __attribute__((ext_vector_type(8)));

union H8P { h8 v; h2 p[4]; };

#if !__has_builtin(__builtin_amdgcn_fdot2)
__device__ __forceinline__ float __builtin_amdgcn_fdot2(h2 a, h2 b, float c, bool) {
  return c + (float)a[0]*(float)b[0] + (float)a[1]*(float)b[1];
}
#endif

// ---------------- setup: fold conv chains into packed matrices ----------------
// Mqkp: f32, packed [c2][o][2]  (flat (cc>>1)*128 + r*2 + (cc&1))
// Mp:   f16, [mat][c2][o][2]    (flat mat*4096 + (cc>>1)*128 + r*2 + (cc&1))
__global__ __launch_bounds__(256) void setup_kernel(
    const float* __restrict__ alpha,
    const float* __restrict__ q_dw, const float* __restrict__ q_pw, const float* __restrict__ q_pb,
    const float* __restrict__ k_dw, const float* __restrict__ k_pw,
    const float* __restrict__ v_dw, const float* __restrict__ v_pw, const float* __restrict__ v_pb,
    const float* __restrict__ o_dw, const float* __restrict__ o_pw, const float* __restrict__ o_pb,
    float* __restrict__ Mqkp, float* __restrict__ qkb,
    _Float16* __restrict__ Mp, float* __restrict__ bout)
{
  int bb = blockIdx.x;
  int tid = threadIdx.x;
  float a = alpha[0];
  if (bb < 16) {
    int e = bb*256 + tid; int r = e >> 6, cc = e & 63;
    float s = 0.f;
    for (int o = 0; o < 64; ++o) s += k_pw[o*64+r]*q_pw[o*64+cc];
    Mqkp[(cc>>1)*128 + r*2 + (cc&1)] = k_dw[r]*q_dw[cc]*s;
  } else if (bb < 32) {
    int e = (bb-16)*256 + tid; int r = e >> 6, cc = e & 63;
    float s = 0.f;
    for (int h = 0; h < 64; ++h) s += o_pw[r*64+h]*o_dw[h]*v_pw[h*64+cc];
    Mp[(cc>>1)*128 + r*2 + (cc&1)] = (_Float16)(a*v_dw[cc]*s);
  } else if (bb < 48) {
    int e = (bb-32)*256 + tid; int r = e >> 6, cc = e & 63;
    float s = 0.f;
    for (int h = 0; h < 64; ++h) s += o_pw[r*64+h]*o_dw[h]*q_pw[h*64+cc];
    Mp[4096 + (cc>>1)*128 + r*2 + (cc&1)] = (_Float16)(q_dw[cc]*s);
  } else {
    if (tid < 64) {
      float s = 0.f;
      for (int o = 0; o < 64; ++o) s += k_pw[o*64+tid]*q_pb[o];
      qkb[tid] = k_dw[tid]*s;
      float s2 = 0.f;
      for (int h = 0; h < 64; ++h) s2 += o_pw[tid*64+h]*o_dw[h]*(a*v_pb[h]+q_pb[h]);
      bout[tid] = o_pb[tid] + s2;
    }
  }
}

// ---------------- transpose x (B,C,H,W) -> xt (B,H,W,C) fp16 -------------------
__global__ __launch_bounds__(256) void transpose_kernel(const float* __restrict__ x,
                                                        _Float16* __restrict__ xt)
{
  __shared__ float t[64][65];
  int i0 = blockIdx.x;
  int blk = (i0 & 7)*128 + (i0 >> 3);
  int b = blk >> 8; int y = (blk >> 1) & 127; int x0 = (blk & 1) << 6;
  int tid = threadIdx.x;
  int p = tid & 63, cq = tid >> 6;
  const float* xb = x + b*CHW + y*128 + x0;
  #pragma unroll
  for (int i = 0; i < 16; ++i) {
    int c = i*4 + cq;
    t[c][p] = xb[c*HW + p];
  }
  __syncthreads();
  int cpair = tid & 31, pq = tid >> 5;
  h2* xtb = (h2*)(xt + (size_t)(b*HW + y*128 + x0)*64);
  #pragma unroll
  for (int i = 0; i < 8; ++i) {
    int pp = i*8 + pq;
    h2 v; v[0] = (_Float16)t[cpair*2][pp]; v[1] = (_Float16)t[cpair*2+1][pp];
    xtb[pp*32 + cpair] = v;
  }
}

// ---------------- fused main kernel: 64 px/block, 512 threads, 8 ch/thread -----
__global__ __launch_bounds__(512, 4) void dam_kernel(
  const float* __restrict__ x, const _Float16* __restrict__ xt,
  const float* __restrict__ offw, const float* __restrict__ offb,
  const float* __restrict__ Mqkp, const float* __restrict__ qkb,
  const _Float16* __restrict__ Mp, const float* __restrict__ bout,
  float* __restrict__ out)
{
  __shared__ _Float16 xs[64][66];     // x tile   [p][c]      8448 B
  __shared__ float offs[18][64];      //                      4608 B
  __shared__ float part[8][9][64];    // [g][k][p]           18432 B ; part[0]=sc ; part[2..] aliased as qs
  __shared__ float MqkL[32*128];      // packed Mqk          16384 B
  __shared__ _Float16 MhL[2*4096];    // packed Mov,Moq      16384 B

  int i0 = blockIdx.x;
  int blk = (i0 & 7)*128 + (i0 >> 3);      // XCD swizzle
  int b = blk >> 8; int y = (blk >> 1) & 127; int x0 = (blk & 1) << 6;
  int tid = threadIdx.x;
  int p = tid & 63;
  int g = tid >> 6;                        // channel group 0..7
  int wg = __builtin_amdgcn_readfirstlane(g);

  // ---- P1: stage x tile (transposed to [p][c]) + matrices + offw scratch ----
  const float* xb = x + b*CHW + y*128 + x0;
  #pragma unroll
  for (int i = 0; i < 8; ++i) {
    int c = i*8 + wg;
    xs[p][c] = (_Float16)xb[c*HW + p];
  }
  #pragma unroll
  for (int i = 0; i < 8; ++i) MqkL[i*512 + tid] = Mqkp[i*512 + tid];
  {
    h2* dst = (h2*)MhL; const h2* src = (const h2*)Mp;
    #pragma unroll
    for (int i = 0; i < 8; ++i) dst[i*512 + tid] = src[i*512 + tid];
  }
  float* offwL = &part[0][0][0];            // scratch during P2 only
  for (int i = tid; i < 18*64; i += 512) offwL[i] = offw[i];
  __syncthreads();

  // ---- P2: qk rows (f32) + offset rows, fused over channel pairs ----
  float qk[8];
  #pragma unroll
  for (int oi = 0; oi < 8; ++oi) qk[oi] = qkb[wg*8+oi];
  float offacc[3];
  int jb = wg*3;                            // rows jb..jb+2 (valid < 18)
  #pragma unroll
  for (int r = 0; r < 3; ++r) offacc[r] = (jb+r < 18) ? offb[jb+r] : 0.f;
  for (int c2 = 0; c2 < 32; ++c2) {
    h2 xv2 = *(const h2*)&xs[p][c2*2];
    float xlo = (float)xv2[0], xhi = (float)xv2[1];
    const float4* pm = (const float4*)&MqkL[c2*128 + wg*16];
    float4 m0 = pm[0], m1 = pm[1], m2 = pm[2], m3 = pm[3];
    qk[0] += m0.x*xlo + m0.y*xhi;  qk[1] += m0.z*xlo + m0.w*xhi;
    qk[2] += m1.x*xlo + m1.y*xhi;  qk[3] += m1.z*xlo + m1.w*xhi;
    qk[4] += m2.x*xlo + m2.y*xhi;  qk[5] += m2.z*xlo + m2.w*xhi;
    qk[6] += m3.x*xlo + m3.y*xhi;  qk[7] += m3.z*xlo + m3.w*xhi;
    #pragma unroll
    for (int r = 0; r < 3; ++r)
      if (jb + r < 18) {
        float2 ow = *(const float2*)&offwL[(jb+r)*64 + c2*2];
        offacc[r] += ow.x*xlo + ow.y*xhi;
      }
  }
  #pragma unroll
  for (int r = 0; r < 3; ++r)
    if (jb + r < 18) offs[jb+r][p] = offacc[r];
  __syncthreads();                          // offs ready; offwL scratch dead

  // ---- P3: single-pass sampling; samples kept in registers ----
  float dxr[9], dyr[9];
  #pragma unroll
  for (int k = 0; k < 9; ++k) { dxr[k] = offs[k][p]; dyr[k] = offs[9+k][p]; }

  h2 qkh[4];
  #pragma unroll
  for (int j = 0; j < 4; ++j) { qkh[j][0] = (_Float16)qk[2*j]; qkh[j][1] = (_Float16)qk[2*j+1]; }

  const _Float16* xtb = xt + (size_t)b*HW*64 + wg*8;
  float fx = (float)(x0 + p);
  float fy = (float)y;

  h2 smp[9][4];
  #pragma unroll
  for (int k = 0; k < 9; ++k) {
    float gx = 2.0f*(fx + dxr[k])/127.0f - 1.0f;
    float gy = 2.0f*(fy + dyr[k])/127.0f - 1.0f;
    float ix = ((gx + 1.0f)*128.0f - 1.0f)*0.5f;
    float iy = ((gy + 1.0f)*128.0f - 1.0f)*0.5f;
    float x0f = floorf(ix), y0f = floorf(iy);
    float wx = ix - x0f, wy = iy - y0f;
    int xi = (int)x0f, yi = (int)y0f;
    bool vx0 = (xi >= 0) && (xi < 128);
    bool vx1 = (xi >= -1) && (xi < 127);
    bool vy0 = (yi >= 0) && (yi < 128);
    bool vy1 = (yi >= -1) && (yi < 127);
    float w00 = (1.f-wy)*(1.f-wx)*((vy0&&vx0)?1.f:0.f);
    float w01 = (1.f-wy)*wx      *((vy0&&vx1)?1.f:0.f);
    float w10 = wy*(1.f-wx)      *((vy1&&vx0)?1.f:0.f);
    float w11 = wy*wx            *((vy1&&vx1)?1.f:0.f);
    int xc0 = min(max(xi,0),127), xc1 = min(max(xi+1,0),127);
    int yc0 = min(max(yi,0),127), yc1 = min(max(yi+1,0),127);
    H8P A, Bc, Cc, D;
    A.v  = *(const h8*)(xtb + (yc0*128 + xc0)*64);
    Bc.v = *(const h8*)(xtb + (yc0*128 + xc1)*64);
    Cc.v = *(const h8*)(xtb + (yc1*128 + xc0)*64);
    D.v  = *(const h8*)(xtb + (yc1*128 + xc1)*64);
    h2 w0h; w0h[0] = (_Float16)w00; w0h[1] = w0h[0];
    h2 w1h; w1h[0] = (_Float16)w01; w1h[1] = w1h[0];
    h2 w2h; w2h[0] = (_Float16)w10; w2h[1] = w2h[0];
    h2 w3h; w3h[0] = (_Float16)w11; w3h[1] = w3h[0];
    float s = 0.f;
    #pragma unroll
    for (int j = 0; j < 4; ++j) {
      h2 v = A.p[j]*w0h + Bc.p[j]*w1h + Cc.p[j]*w2h + D.p[j]*w3h;
      smp[k][j] = v;
      s = __builtin_amdgcn_fdot2(v, qkh[j], s, false);
    }
    part[g][k][p] = s;
  }
  __syncthreads();

  // ---- P4: reduce partials (into part[0]) + softmax over k ----
  float (*sc)[64] = part[0];
  for (int e = tid; e < 9*64; e += 512) {
    int k = e >> 6, pp = e & 63;
    float s = 0.f;
    #pragma unroll
    for (int g2 = 0; g2 < 8; ++g2) s += part[g2][k][pp];
    sc[k][pp] = s;
  }
  __syncthreads();
  if (tid < 64) {
    float m = sc[0][tid];
    #pragma unroll
    for (int k = 1; k < 9; ++k) m = fmaxf(m, sc[k][tid]);
    float s = 0.f;
    #pragma unroll
    for (int k = 0; k < 9; ++k) { float e2 = __expf(sc[k][tid]-m); s += e2; sc[k][tid] = e2; }
    float inv = 1.f/s;
    #pragma unroll
    for (int k = 0; k < 9; ++k) sc[k][tid] *= inv;
  }
  __syncthreads();

  // ---- P5: S = sum_k attn_k * smp_k (pure VALU, no loads) ----
  h2 S2[4];
  #pragma unroll
  for (int j = 0; j < 4; ++j) { S2[j][0] = (_Float16)0.f; S2[j][1] = (_Float16)0.f; }
  #pragma unroll
  for (int k = 0; k < 9; ++k) {
    h2 ak; ak[0] = (_Float16)sc[k][p]; ak[1] = ak[0];
    #pragma unroll
    for (int j = 0; j < 4; ++j) S2[j] = S2[j] + ak*smp[k][j];
  }
  // write S slice into qs (aliases part[2..], disjoint from sc=part[0])
  _Float16 (*qs)[66] = (_Float16 (*)[66])&part[2][0][0];
  #pragma unroll
  for (int j = 0; j < 4; ++j) *(h2*)&qs[p][wg*8 + 2*j] = S2[j];
  __syncthreads();

  // ---- P6: out rows = Mov@S + Moq@x + bout via fdot2, packed-uniform M reads --
  float acc[8];
  #pragma unroll
  for (int oi = 0; oi < 8; ++oi) acc[oi] = bout[wg*8+oi];
  for (int c2 = 0; c2 < 32; ++c2) {
    h2 sv2 = *(const h2*)&qs[p][c2*2];
    h2 xv2 = *(const h2*)&xs[p][c2*2];
    H8P ma, mb, mc, md;
    const h8* pm0 = (const h8*)&MhL[c2*128 + wg*16];
    ma.v = pm0[0]; mb.v = pm0[1];
    const h8* pm1 = (const h8*)&MhL[4096 + c2*128 + wg*16];
    mc.v = pm1[0]; md.v = pm1[1];
    #pragma unroll
    for (int oi = 0; oi < 4; ++oi) {
      acc[oi] = __builtin_amdgcn_fdot2(ma.p[oi], sv2, acc[oi], false);
      acc[oi] = __builtin_amdgcn_fdot2(mc.p[oi], xv2, acc[oi], false);
    }
    #pragma unroll
    for (int oi = 0; oi < 4; ++oi) {
      acc[4+oi] = __builtin_amdgcn_fdot2(mb.p[oi], sv2, acc[4+oi], false);
      acc[4+oi] = __builtin_amdgcn_fdot2(md.p[oi], xv2, acc[4+oi], false);
    }
  }
  float* ob = out + b*CHW + y*128 + x0;
  #pragma unroll
  for (int oi = 0; oi < 8; ++oi) ob[(wg*8+oi)*HW + p] = acc[oi];
}

extern "C" void kernel_launch(void* const* d_in, const int* in_sizes, int n_in,
                              void* d_out, int out_size, void* d_ws, size_t ws_size,
                              hipStream_t stream)
{
  const float* x    = (const float*)d_in[0];
  const float* alpha= (const float*)d_in[1];
  const float* offw = (const float*)d_in[2];
  const float* offb = (const float*)d_in[3];
  const float* q_dw = (const float*)d_in[4];
  const float* q_pw = (const float*)d_in[5];
  const float* q_pb = (const float*)d_in[6];
  const float* k_dw = (const float*)d_in[7];
  const float* k_pw = (const float*)d_in[8];
  const float* v_dw = (const float*)d_in[10];
  const float* v_pw = (const float*)d_in[11];
  const float* v_pb = (const float*)d_in[12];
  const float* o_dw = (const float*)d_in[13];
  const float* o_pw = (const float*)d_in[14];
  const float* o_pb = (const float*)d_in[15];
  float* out = (float*)d_out;

  char* ws      = (char*)d_ws;
  _Float16* xt  = (_Float16*)ws;                                  // 8.4 MB
  float* Mqkp   = (float*)(ws + (size_t)4*HW*64*sizeof(_Float16));
  _Float16* Mp  = (_Float16*)(Mqkp + 4096);                       // 8192 halves
  float* qkb    = (float*)(Mp + 8192);
  float* bout   = qkb + 64;

  setup_kernel<<<49, 256, 0, stream>>>(alpha, q_dw, q_pw, q_pb, k_dw, k_pw,
                                       v_dw, v_pw, v_pb, o_dw, o_pw, o_pb,
                                       Mqkp, qkb, Mp, bout);
  transpose_kernel<<<1024, 256, 0, stream>>>(x, xt);
  dam_kernel<<<1024, 512, 0, stream>>>(x, xt, offw, offb, Mqkp, qkb, Mp, bout, out);
}

// Round 5
// 52.298 us; speedup vs baseline: 3.6419x; 1.3856x over previous
//
#include <hip/hip_runtime.h>

#define HW (128*128)
#define CHW (64*HW)

typedef _Float16 h2 __attribute__((ext_vector_type(2)));
typedef _Float16 h4 __attribute__((ext_vector_type(4)));
typedef _Float16 h8 __attribute__((ext_vector_type(8)));
typedef float f32x4 __attribute__((ext_vector_type(4)));

union H8P { h8 v; h2 p[4]; };

#if !__has_builtin(__builtin_amdgcn_fdot2)
__device__ __forceinline__ float __builtin_amdgcn_fdot2(h2 a, h2 b, float c, bool) {
  return c + (float)a[0]*(float)b[0] + (float)a[1]*(float)b[1];
}
#endif

// ---------------- setup: fold conv chains into MFMA A-fragment-packed matrices ---------
// Apack2: [6 mtile][2 ktile][64 lane][8] f16 ; rows 0-63 = Mqk, 64-81 = offw, 82-95 = 0
// Apack6: [4 mtile][4 ktile][64 lane][8] f16 ; K 0-63 = Mov (S), 64-127 = Moq (x)
// bias96: f32[96] (qkb | offb | 0) ; boutd: f32[64]
__global__ __launch_bounds__(256) void setup_kernel(
    const float* __restrict__ alpha,
    const float* __restrict__ q_dw, const float* __restrict__ q_pw, const float* __restrict__ q_pb,
    const float* __restrict__ k_dw, const float* __restrict__ k_pw,
    const float* __restrict__ offw, const float* __restrict__ offb,
    const float* __restrict__ v_dw, const float* __restrict__ v_pw, const float* __restrict__ v_pb,
    const float* __restrict__ o_dw, const float* __restrict__ o_pw, const float* __restrict__ o_pb,
    _Float16* __restrict__ Apack2, _Float16* __restrict__ Apack6,
    float* __restrict__ bias96, float* __restrict__ boutd)
{
  int bb = blockIdx.x;
  int tid = threadIdx.x;
  float a = alpha[0];
  if (bb < 24) {                       // Apack2: 6144 elements
    int e = bb*256 + tid;
    int j = e & 7, l = (e >> 3) & 63, kt = (e >> 9) & 1, mt = e >> 10;
    int row = mt*16 + (l & 15);
    int c   = kt*32 + (l >> 4)*8 + j;
    float v = 0.f;
    if (row < 64) {
      float s = 0.f;
      for (int o = 0; o < 64; ++o) s += k_pw[o*64+row]*q_pw[o*64+c];
      v = k_dw[row]*q_dw[c]*s;
    } else if (row < 82) {
      v = offw[(row-64)*64 + c];
    }
    Apack2[e] = (_Float16)v;
  } else if (bb < 56) {                // Apack6: 8192 elements
    int e = (bb-24)*256 + tid;
    int j = e & 7, l = (e >> 3) & 63, kt = (e >> 9) & 3, mt = e >> 11;
    int o  = mt*16 + (l & 15);
    int cc = kt*32 + (l >> 4)*8 + j;
    float v;
    if (cc < 64) {
      float s = 0.f;
      for (int h = 0; h < 64; ++h) s += o_pw[o*64+h]*o_dw[h]*v_pw[h*64+cc];
      v = a*v_dw[cc]*s;
    } else {
      int c2 = cc - 64;
      float s = 0.f;
      for (int h = 0; h < 64; ++h) s += o_pw[o*64+h]*o_dw[h]*q_pw[h*64+c2];
      v = q_dw[c2]*s;
    }
    Apack6[e] = (_Float16)v;
  } else {
    if (tid < 96) {
      float v = 0.f;
      if (tid < 64) {
        float s = 0.f;
        for (int o = 0; o < 64; ++o) s += k_pw[o*64+tid]*q_pb[o];
        v = k_dw[tid]*s;
      } else if (tid < 82) {
        v = offb[tid-64];
      }
      bias96[tid] = v;
    } else if (tid >= 128 && tid < 192) {
      int o = tid - 128;
      float s2 = 0.f;
      for (int h = 0; h < 64; ++h) s2 += o_pw[o*64+h]*o_dw[h]*(a*v_pb[h]+q_pb[h]);
      boutd[o] = o_pb[o] + s2;
    }
  }
}

// ---------------- transpose x (B,C,H,W) -> xt (B,H,W,C) fp16 -------------------
__global__ __launch_bounds__(256) void transpose_kernel(const float* __restrict__ x,
                                                        _Float16* __restrict__ xt)
{
  __shared__ float t[64][65];
  int i0 = blockIdx.x;
  int blk = (i0 & 7)*128 + (i0 >> 3);
  int b = blk >> 8; int y = (blk >> 1) & 127; int x0 = (blk & 1) << 6;
  int tid = threadIdx.x;
  int p = tid & 63, cq = tid >> 6;
  const float* xb = x + b*CHW + y*128 + x0;
  #pragma unroll
  for (int i = 0; i < 16; ++i) {
    int c = i*4 + cq;
    t[c][p] = xb[c*HW + p];
  }
  __syncthreads();
  int cpair = tid & 31, pq = tid >> 5;
  h2* xtb = (h2*)(xt + (size_t)(b*HW + y*128 + x0)*64);
  #pragma unroll
  for (int i = 0; i < 8; ++i) {
    int pp = i*8 + pq;
    h2 v; v[0] = (_Float16)t[cpair*2][pp]; v[1] = (_Float16)t[cpair*2+1][pp];
    xtb[pp*32 + cpair] = v;
  }
}

// ---------------- fused main kernel: 64 px/block, 512 threads, MFMA matvecs -----
__global__ __launch_bounds__(512, 8) void dam_kernel(
  const float* __restrict__ x, const _Float16* __restrict__ xt,
  const _Float16* __restrict__ Apack2, const _Float16* __restrict__ Apack6,
  const float* __restrict__ bias96, const float* __restrict__ boutd,
  float* __restrict__ out)
{
  __shared__ __align__(16) _Float16 xs[64][72];   // x tile [p][c]   9216 B (stride 72 -> 16B rows)
  __shared__ __align__(16) _Float16 qkL[64][72];  // qk     [p][o]   9216 B
  __shared__ __align__(16) float pool[8*9*64];    // 18432 B: offs[18][64] | part[8][9][64] | qs f16

  float (*offsF)[64] = (float (*)[64])pool;                    // P2 out, dead after P3 reg-load
  _Float16 (*qs)[72] = (_Float16 (*)[72])((char*)pool + 4608); // S tile, written P5 (part[2..5])

  int i0 = blockIdx.x;
  int blk = (i0 & 7)*128 + (i0 >> 3);      // XCD swizzle
  int b = blk >> 8; int y = (blk >> 1) & 127; int x0 = (blk & 1) << 6;
  int tid = threadIdx.x;
  int p = tid & 63;
  int g = tid >> 6;
  int wg = __builtin_amdgcn_readfirstlane(g);
  int lane = tid & 63;

  // ---- P1: stage x tile [p][c] f16 ----
  const float* xb = x + b*CHW + y*128 + x0;
  #pragma unroll
  for (int i = 0; i < 8; ++i) {
    int c = i*8 + wg;
    xs[p][c] = (_Float16)xb[c*HW + p];
  }
  __syncthreads();

  // ---- P2: [qk | offsets] = A2 @ x_tile via MFMA. M=96, K=64, N=64 ----
  // wave wg handles tiles t = 3wg .. 3wg+2 ; m = t>>2, n = t&3
  {
    const h8* A2 = (const h8*)Apack2;
    #pragma unroll
    for (int i = 0; i < 3; ++i) {
      int t = wg*3 + i; int m = t >> 2, n = t & 3;
      int row0 = m*16 + (lane >> 4)*4;
      int pcol = n*16 + (lane & 15);
      f32x4 acc;
      #pragma unroll
      for (int r = 0; r < 4; ++r) acc[r] = bias96[row0 + r];
      h8 b0 = *(const h8*)&xs[pcol][(lane >> 4)*8];
      h8 b1 = *(const h8*)&xs[pcol][32 + (lane >> 4)*8];
      acc = __builtin_amdgcn_mfma_f32_16x16x32_f16(A2[(m*2+0)*64 + lane], b0, acc, 0, 0, 0);
      acc = __builtin_amdgcn_mfma_f32_16x16x32_f16(A2[(m*2+1)*64 + lane], b1, acc, 0, 0, 0);
      if (m < 4) {
        h4 v;
        #pragma unroll
        for (int r = 0; r < 4; ++r) v[r] = (_Float16)acc[r];
        *(h4*)&qkL[pcol][m*16 + (lane >> 4)*4] = v;
      } else {
        #pragma unroll
        for (int r = 0; r < 4; ++r) {
          int row = row0 + r;
          if (row < 82) offsF[row - 64][pcol] = acc[r];
        }
      }
    }
  }
  __syncthreads();

  // ---- P3 prelude: hoist offsets + qk slice to registers, then free offs region ----
  float dxr[9], dyr[9];
  #pragma unroll
  for (int k = 0; k < 9; ++k) { dxr[k] = offsF[k][p]; dyr[k] = offsF[9+k][p]; }
  H8P qkh; qkh.v = *(const h8*)&qkL[p][wg*8];
  __syncthreads();                          // all reads done; pool now free for part[]

  const _Float16* xtb = xt + (size_t)b*HW*64 + wg*8;
  float fx = (float)(x0 + p);
  float fy = (float)y;

  // ---- P3: single-pass sampling; samples kept in registers; partial scores -> pool ----
  h2 smp[9][4];
  #pragma unroll
  for (int k = 0; k < 9; ++k) {
    float gx = 2.0f*(fx + dxr[k])/127.0f - 1.0f;
    float gy = 2.0f*(fy + dyr[k])/127.0f - 1.0f;
    float ix = ((gx + 1.0f)*128.0f - 1.0f)*0.5f;
    float iy = ((gy + 1.0f)*128.0f - 1.0f)*0.5f;
    float x0f = floorf(ix), y0f = floorf(iy);
    float wx = ix - x0f, wy = iy - y0f;
    int xi = (int)x0f, yi = (int)y0f;
    bool vx0 = (xi >= 0) && (xi < 128);
    bool vx1 = (xi >= -1) && (xi < 127);
    bool vy0 = (yi >= 0) && (yi < 128);
    bool vy1 = (yi >= -1) && (yi < 127);
    float w00 = (1.f-wy)*(1.f-wx)*((vy0&&vx0)?1.f:0.f);
    float w01 = (1.f-wy)*wx      *((vy0&&vx1)?1.f:0.f);
    float w10 = wy*(1.f-wx)      *((vy1&&vx0)?1.f:0.f);
    float w11 = wy*wx            *((vy1&&vx1)?1.f:0.f);
    int xc0 = min(max(xi,0),127), xc1 = min(max(xi+1,0),127);
    int yc0 = min(max(yi,0),127), yc1 = min(max(yi+1,0),127);
    H8P A, Bc, Cc, D;
    A.v  = *(const h8*)(xtb + (yc0*128 + xc0)*64);
    Bc.v = *(const h8*)(xtb + (yc0*128 + xc1)*64);
    Cc.v = *(const h8*)(xtb + (yc1*128 + xc0)*64);
    D.v  = *(const h8*)(xtb + (yc1*128 + xc1)*64);
    h2 w0h; w0h[0] = (_Float16)w00; w0h[1] = w0h[0];
    h2 w1h; w1h[0] = (_Float16)w01; w1h[1] = w1h[0];
    h2 w2h; w2h[0] = (_Float16)w10; w2h[1] = w2h[0];
    h2 w3h; w3h[0] = (_Float16)w11; w3h[1] = w3h[0];
    float s = 0.f;
    #pragma unroll
    for (int j = 0; j < 4; ++j) {
      h2 v = A.p[j]*w0h + Bc.p[j]*w1h + Cc.p[j]*w2h + D.p[j]*w3h;
      smp[k][j] = v;
      s = __builtin_amdgcn_fdot2(v, qkh.p[j], s, false);
    }
    pool[g*576 + k*64 + p] = s;             // part[g][k][p]
  }
  __syncthreads();

  // ---- P4: reduce partials (into part[0]) + softmax over k ----
  float (*sc)[64] = (float (*)[64])pool;
  for (int e = tid; e < 9*64; e += 512) {
    int k = e >> 6, pp = e & 63;
    float s = 0.f;
    #pragma unroll
    for (int g2 = 0; g2 < 8; ++g2) s += pool[g2*576 + k*64 + pp];
    sc[k][pp] = s;
  }
  __syncthreads();
  if (tid < 64) {
    float m = sc[0][tid];
    #pragma unroll
    for (int k = 1; k < 9; ++k) m = fmaxf(m, sc[k][tid]);
    float s = 0.f;
    #pragma unroll
    for (int k = 0; k < 9; ++k) { float e2 = __expf(sc[k][tid]-m); s += e2; sc[k][tid] = e2; }
    float inv = 1.f/s;
    #pragma unroll
    for (int k = 0; k < 9; ++k) sc[k][tid] *= inv;
  }
  __syncthreads();

  // ---- P5: S = sum_k attn_k * smp_k ; write S tile [p][c] f16 (aliases part[2..5]) ----
  {
    h2 S2[4];
    #pragma unroll
    for (int j = 0; j < 4; ++j) { S2[j][0] = (_Float16)0.f; S2[j][1] = (_Float16)0.f; }
    #pragma unroll
    for (int k = 0; k < 9; ++k) {
      h2 ak; ak[0] = (_Float16)sc[k][p]; ak[1] = ak[0];
      #pragma unroll
      for (int j = 0; j < 4; ++j) S2[j] = S2[j] + ak*smp[k][j];
    }
    #pragma unroll
    for (int j = 0; j < 4; ++j) *(h2*)&qs[p][wg*8 + 2*j] = S2[j];
  }
  __syncthreads();

  // ---- P6: out = A6 @ [S; x] + bout via MFMA. M=64, K=128, N=64 ----
  // wave wg handles tiles t = 2wg, 2wg+1 ; m = t>>2, n = t&3
  {
    const h8* A6 = (const h8*)Apack6;
    float* ob = out + b*CHW + y*128 + x0;
    #pragma unroll
    for (int i = 0; i < 2; ++i) {
      int t = wg*2 + i; int m = t >> 2, n = t & 3;
      int row0 = m*16 + (lane >> 4)*4;
      int pcol = n*16 + (lane & 15);
      f32x4 acc;
      #pragma unroll
      for (int r = 0; r < 4; ++r) acc[r] = boutd[row0 + r];
      h8 b0 = *(const h8*)&qs[pcol][(lane >> 4)*8];
      h8 b1 = *(const h8*)&qs[pcol][32 + (lane >> 4)*8];
      h8 b2 = *(const h8*)&xs[pcol][(lane >> 4)*8];
      h8 b3 = *(const h8*)&xs[pcol][32 + (lane >> 4)*8];
      acc = __builtin_amdgcn_mfma_f32_16x16x32_f16(A6[(m*4+0)*64 + lane], b0, acc, 0, 0, 0);
      acc = __builtin_amdgcn_mfma_f32_16x16x32_f16(A6[(m*4+1)*64 + lane], b1, acc, 0, 0, 0);
      acc = __builtin_amdgcn_mfma_f32_16x16x32_f16(A6[(m*4+2)*64 + lane], b2, acc, 0, 0, 0);
      acc = __builtin_amdgcn_mfma_f32_16x16x32_f16(A6[(m*4+3)*64 + lane], b3, acc, 0, 0, 0);
      #pragma unroll
      for (int r = 0; r < 4; ++r) ob[(row0 + r)*HW + pcol] = acc[r];
    }
  }
}

extern "C" void kernel_launch(void* const* d_in, const int* in_sizes, int n_in,
                              void* d_out, int out_size, void* d_ws, size_t ws_size,
                              hipStream_t stream)
{
  const float* x    = (const float*)d_in[0];
  const float* alpha= (const float*)d_in[1];
  const float* offw = (const float*)d_in[2];
  const float* offb = (const float*)d_in[3];
  const float* q_dw = (const float*)d_in[4];
  const float* q_pw = (const float*)d_in[5];
  const float* q_pb = (const float*)d_in[6];
  const float* k_dw = (const float*)d_in[7];
  const float* k_pw = (const float*)d_in[8];
  const float* v_dw = (const float*)d_in[10];
  const float* v_pw = (const float*)d_in[11];
  const float* v_pb = (const float*)d_in[12];
  const float* o_dw = (const float*)d_in[13];
  const float* o_pw = (const float*)d_in[14];
  const float* o_pb = (const float*)d_in[15];
  float* out = (float*)d_out;

  char* ws        = (char*)d_ws;
  _Float16* xt    = (_Float16*)ws;                          // 8,388,608 B
  _Float16* Apack2= (_Float16*)(ws + (size_t)4*HW*64*2);    // 12288 B
  _Float16* Apack6= Apack2 + 6144;                          // 16384 B
  float* bias96   = (float*)(Apack6 + 8192);
  float* boutd    = bias96 + 96;

  setup_kernel<<<57, 256, 0, stream>>>(alpha, q_dw, q_pw, q_pb, k_dw, k_pw,
                                       offw, offb, v_dw, v_pw, v_pb,
                                       o_dw, o_pw, o_pb,
                                       Apack2, Apack6, bias96, boutd);
  transpose_kernel<<<1024, 256, 0, stream>>>(x, xt);
  dam_kernel<<<1024, 512, 0, stream>>>(x, xt, Apack2, Apack6, bias96, boutd, out);
}

// Round 6
// 50.100 us; speedup vs baseline: 3.8017x; 1.0439x over previous
//
#include <hip/hip_runtime.h>

#define HW (128*128)
#define CHW (64*HW)

typedef _Float16 h2 __attribute__((ext_vector_type(2)));
typedef _Float16 h4 __attribute__((ext_vector_type(4)));
typedef _Float16 h8 __attribute__((ext_vector_type(8)));
typedef float f32x4 __attribute__((ext_vector_type(4)));

union H8P { h8 v; h2 p[4]; };
union H4P { h4 v; h2 p[2]; };

#if !__has_builtin(__builtin_amdgcn_fdot2)
__device__ __forceinline__ float __builtin_amdgcn_fdot2(h2 a, h2 b, float c, bool) {
  return c + (float)a[0]*(float)b[0] + (float)a[1]*(float)b[1];
}
#endif

// ---------------- transpose + setup fused (independent work, one launch) ----------------
// blocks 0..1023: transpose x -> xt (B,H,W,C) f16
// blocks 1024..1080: fold conv chains into MFMA A-fragment-packed matrices
__global__ __launch_bounds__(256) void prep_kernel(
    const float* __restrict__ x, _Float16* __restrict__ xt,
    const float* __restrict__ alpha,
    const float* __restrict__ q_dw, const float* __restrict__ q_pw, const float* __restrict__ q_pb,
    const float* __restrict__ k_dw, const float* __restrict__ k_pw,
    const float* __restrict__ offw, const float* __restrict__ offb,
    const float* __restrict__ v_dw, const float* __restrict__ v_pw, const float* __restrict__ v_pb,
    const float* __restrict__ o_dw, const float* __restrict__ o_pw, const float* __restrict__ o_pb,
    _Float16* __restrict__ Apack2, _Float16* __restrict__ Apack6,
    float* __restrict__ bias96, float* __restrict__ boutd)
{
  int tid = threadIdx.x;
  if (blockIdx.x < 1024) {
    __shared__ float t[64][65];
    int i0 = blockIdx.x;
    int blk = (i0 & 7)*128 + (i0 >> 3);
    int b = blk >> 8; int y = (blk >> 1) & 127; int x0 = (blk & 1) << 6;
    int p = tid & 63, cq = tid >> 6;
    const float* xb = x + b*CHW + y*128 + x0;
    #pragma unroll
    for (int i = 0; i < 16; ++i) {
      int c = i*4 + cq;
      t[c][p] = xb[c*HW + p];
    }
    __syncthreads();
    int cpair = tid & 31, pq = tid >> 5;
    h2* xtb = (h2*)(xt + (size_t)(b*HW + y*128 + x0)*64);
    #pragma unroll
    for (int i = 0; i < 8; ++i) {
      int pp = i*8 + pq;
      h2 v; v[0] = (_Float16)t[cpair*2][pp]; v[1] = (_Float16)t[cpair*2+1][pp];
      xtb[pp*32 + cpair] = v;
    }
    return;
  }
  int bb = blockIdx.x - 1024;
  float a = alpha[0];
  if (bb < 24) {                       // Apack2: [6 mt][2 kt][64 lane][8]
    int e = bb*256 + tid;
    int j = e & 7, l = (e >> 3) & 63, kt = (e >> 9) & 1, mt = e >> 10;
    int row = mt*16 + (l & 15);
    int c   = kt*32 + (l >> 4)*8 + j;
    float v = 0.f;
    if (row < 64) {
      float s = 0.f;
      for (int o = 0; o < 64; ++o) s += k_pw[o*64+row]*q_pw[o*64+c];
      v = k_dw[row]*q_dw[c]*s;
    } else if (row < 82) {
      v = offw[(row-64)*64 + c];
    }
    Apack2[e] = (_Float16)v;
  } else if (bb < 56) {                // Apack6: [4 mt][4 kt][64 lane][8]
    int e = (bb-24)*256 + tid;
    int j = e & 7, l = (e >> 3) & 63, kt = (e >> 9) & 3, mt = e >> 11;
    int o  = mt*16 + (l & 15);
    int cc = kt*32 + (l >> 4)*8 + j;
    float v;
    if (cc < 64) {
      float s = 0.f;
      for (int h = 0; h < 64; ++h) s += o_pw[o*64+h]*o_dw[h]*v_pw[h*64+cc];
      v = a*v_dw[cc]*s;
    } else {
      int c2 = cc - 64;
      float s = 0.f;
      for (int h = 0; h < 64; ++h) s += o_pw[o*64+h]*o_dw[h]*q_pw[h*64+c2];
      v = q_dw[c2]*s;
    }
    Apack6[e] = (_Float16)v;
  } else {
    if (tid < 96) {
      float v = 0.f;
      if (tid < 64) {
        float s = 0.f;
        for (int o = 0; o < 64; ++o) s += k_pw[o*64+tid]*q_pb[o];
        v = k_dw[tid]*s;
      } else if (tid < 82) {
        v = offb[tid-64];
      }
      bias96[tid] = v;
    } else if (tid >= 128 && tid < 192) {
      int o = tid - 128;
      float s2 = 0.f;
      for (int h = 0; h < 64; ++h) s2 += o_pw[o*64+h]*o_dw[h]*(a*v_pb[h]+q_pb[h]);
      boutd[o] = o_pb[o] + s2;
    }
  }
}

// ---------------- fused main kernel: 64 px/block, 512 threads ------------------
// LDS layout (36864 B total):
//  A [0,9216):      xs f16 [64][72]                 live P1..P6
//  B [9216,18432):  qkL f16 [64][72] (P2..prelude) | part[0..3] (P3/P4) | qs f16 (P5/P6)
//  C [18432,23040): offsF f32 [18][64] (P2..param) | part[4..5]
//  D [23040,27648): part[6..7] ; sc f32[9][64] = part[6] (P4..P5)
//  E [27648,36864): addrLds int2[576] + wtLds h4[576]  (param..P3)
__global__ __launch_bounds__(512, 8) void dam_kernel(
  const float* __restrict__ x, const _Float16* __restrict__ xt,
  const _Float16* __restrict__ Apack2, const _Float16* __restrict__ Apack6,
  const float* __restrict__ bias96, const float* __restrict__ boutd,
  float* __restrict__ out)
{
  __shared__ __align__(16) char lds[36864];
  _Float16 (*xs)[72]  = (_Float16 (*)[72])lds;
  _Float16 (*qkL)[72] = (_Float16 (*)[72])(lds + 9216);
  float (*offsF)[64]  = (float (*)[64])(lds + 18432);
  float* part         = (float*)(lds + 9216);          // [8][9][64]
  float (*sc)[64]     = (float (*)[64])(lds + 23040);  // = part[6]
  _Float16 (*qs)[72]  = (_Float16 (*)[72])(lds + 9216);
  int2* addrLds       = (int2*)(lds + 27648);          // [576]
  h4*  wtLds          = (h4*)(lds + 32256);            // [576]

  int i0 = blockIdx.x;
  int blk = (i0 & 7)*128 + (i0 >> 3);      // XCD swizzle
  int b = blk >> 8; int y = (blk >> 1) & 127; int x0 = (blk & 1) << 6;
  int tid = threadIdx.x;
  int p = tid & 63;
  int g = tid >> 6;
  int wg = __builtin_amdgcn_readfirstlane(g);
  int lane = tid & 63;

  // ---- P1: stage x tile [p][c] f16 ; one b128 write per thread ----
  const float* xb = x + b*CHW + y*128 + x0;
  {
    h8 v;
    #pragma unroll
    for (int i = 0; i < 8; ++i) v[i] = (_Float16)xb[(wg*8 + i)*HW + p];
    *(h8*)&xs[p][wg*8] = v;
  }
  __syncthreads();

  // ---- P2: [qk | offsets] = A2 @ x_tile via MFMA. M=96, K=64, N=64 ----
  {
    const h8* A2 = (const h8*)Apack2;
    #pragma unroll
    for (int i = 0; i < 3; ++i) {
      int t = wg*3 + i; int m = t >> 2, n = t & 3;
      int row0 = m*16 + (lane >> 4)*4;
      int pcol = n*16 + (lane & 15);
      f32x4 acc;
      #pragma unroll
      for (int r = 0; r < 4; ++r) acc[r] = bias96[row0 + r];
      h8 b0 = *(const h8*)&xs[pcol][(lane >> 4)*8];
      h8 b1 = *(const h8*)&xs[pcol][32 + (lane >> 4)*8];
      acc = __builtin_amdgcn_mfma_f32_16x16x32_f16(A2[(m*2+0)*64 + lane], b0, acc, 0, 0, 0);
      acc = __builtin_amdgcn_mfma_f32_16x16x32_f16(A2[(m*2+1)*64 + lane], b1, acc, 0, 0, 0);
      if (m < 4) {
        h4 v;
        #pragma unroll
        for (int r = 0; r < 4; ++r) v[r] = (_Float16)acc[r];
        *(h4*)&qkL[pcol][m*16 + (lane >> 4)*4] = v;
      } else {
        #pragma unroll
        for (int r = 0; r < 4; ++r) {
          int row = row0 + r;
          if (row < 82) offsF[row - 64][pcol] = acc[r];
        }
      }
    }
  }
  __syncthreads();

  // ---- P2.5: per-(k,p) sampling params, computed ONCE ----
  // (reads offsF in C; writes addr/wt into E); also hoist qk slice from B
  H8P qkh; qkh.v = *(const h8*)&qkL[p][wg*8];
  #pragma unroll
  for (int pass = 0; pass < 2; ++pass) {
    int e = tid + pass*512;
    if (e < 576) {
      int k = e >> 6, pp = e & 63;
      float dx = offsF[k][pp];
      float dy = offsF[9+k][pp];
      float fx = (float)(x0 + pp);
      float fy = (float)y;
      float gx = 2.0f*(fx + dx)/127.0f - 1.0f;
      float gy = 2.0f*(fy + dy)/127.0f - 1.0f;
      float ix = ((gx + 1.0f)*128.0f - 1.0f)*0.5f;
      float iy = ((gy + 1.0f)*128.0f - 1.0f)*0.5f;
      float x0f = floorf(ix), y0f = floorf(iy);
      float wx = ix - x0f, wy = iy - y0f;
      int xi = (int)x0f, yi = (int)y0f;
      bool vx0 = (xi >= 0) && (xi < 128);
      bool vx1 = (xi >= -1) && (xi < 127);
      bool vy0 = (yi >= 0) && (yi < 128);
      bool vy1 = (yi >= -1) && (yi < 127);
      h4 w;
      w[0] = (_Float16)((1.f-wy)*(1.f-wx)*((vy0&&vx0)?1.f:0.f));
      w[1] = (_Float16)((1.f-wy)*wx      *((vy0&&vx1)?1.f:0.f));
      w[2] = (_Float16)(wy*(1.f-wx)      *((vy1&&vx0)?1.f:0.f));
      w[3] = (_Float16)(wy*wx            *((vy1&&vx1)?1.f:0.f));
      int xc0 = min(max(xi,0),127), xc1 = min(max(xi+1,0),127);
      int yc0 = min(max(yi,0),127), yc1 = min(max(yi+1,0),127);
      int2 ap;
      ap.x = (yc0*128 + xc0)*64;
      ap.y = (xc1 - xc0)*64 | (((yc1 - yc0)*8192) << 16);
      addrLds[e] = ap;
      wtLds[e] = w;
    }
  }
  __syncthreads();      // params ready; B/C/D become part[]

  const _Float16* xtb = xt + (size_t)b*HW*64 + wg*8;

  // ---- P3: single-pass sampling; samples kept in registers; partials -> part ----
  h2 smp[9][4];
  #pragma unroll
  for (int k = 0; k < 9; ++k) {
    int2 ap = addrLds[k*64 + p];
    H4P w; w.v = wtLds[k*64 + p];
    int dxs = ap.y & 0xFFFF;
    int dys = ap.y >> 16;
    const _Float16* base = xtb + ap.x;
    H8P A, Bc, Cc, D;
    A.v  = *(const h8*)(base);
    Bc.v = *(const h8*)(base + dxs);
    Cc.v = *(const h8*)(base + dys);
    D.v  = *(const h8*)(base + dys + dxs);
    h2 w0h; w0h[0] = w.v[0]; w0h[1] = w.v[0];
    h2 w1h; w1h[0] = w.v[1]; w1h[1] = w.v[1];
    h2 w2h; w2h[0] = w.v[2]; w2h[1] = w.v[2];
    h2 w3h; w3h[0] = w.v[3]; w3h[1] = w.v[3];
    float s = 0.f;
    #pragma unroll
    for (int j = 0; j < 4; ++j) {
      h2 v = A.p[j]*w0h + Bc.p[j]*w1h + Cc.p[j]*w2h + D.p[j]*w3h;
      smp[k][j] = v;
      s = __builtin_amdgcn_fdot2(v, qkh.p[j], s, false);
    }
    part[g*576 + k*64 + p] = s;
  }
  __syncthreads();

  // ---- P4: reduce partials -> sc (=part[6], safe) + softmax over k ----
  for (int e = tid; e < 576; e += 512) {
    int k = e >> 6, pp = e & 63;
    float s = 0.f;
    #pragma unroll
    for (int g2 = 0; g2 < 8; ++g2) s += part[g2*576 + k*64 + pp];
    sc[k][pp] = s;
  }
  __syncthreads();
  if (tid < 64) {
    float m = sc[0][tid];
    #pragma unroll
    for (int k = 1; k < 9; ++k) m = fmaxf(m, sc[k][tid]);
    float s = 0.f;
    #pragma unroll
    for (int k = 0; k < 9; ++k) { float e2 = __expf(sc[k][tid]-m); s += e2; sc[k][tid] = e2; }
    float inv = 1.f/s;
    #pragma unroll
    for (int k = 0; k < 9; ++k) sc[k][tid] *= inv;
  }
  __syncthreads();

  // ---- P5: S = sum_k attn_k * smp_k ; write S tile [p][c] f16 into B ----
  {
    h2 S2[4];
    #pragma unroll
    for (int j = 0; j < 4; ++j) { S2[j][0] = (_Float16)0.f; S2[j][1] = (_Float16)0.f; }
    #pragma unroll
    for (int k = 0; k < 9; ++k) {
      h2 ak; ak[0] = (_Float16)sc[k][p]; ak[1] = ak[0];
      #pragma unroll
      for (int j = 0; j < 4; ++j) S2[j] = S2[j] + ak*smp[k][j];
    }
    H4P lo; lo.p[0] = S2[0]; lo.p[1] = S2[1];
    H4P hi; hi.p[0] = S2[2]; hi.p[1] = S2[3];
    *(h4*)&qs[p][wg*8]     = lo.v;
    *(h4*)&qs[p][wg*8 + 4] = hi.v;
  }
  __syncthreads();

  // ---- P6: out = A6 @ [S; x] + bout via MFMA. M=64, K=128, N=64 ----
  {
    const h8* A6 = (const h8*)Apack6;
    float* ob = out + b*CHW + y*128 + x0;
    #pragma unroll
    for (int i = 0; i < 2; ++i) {
      int t = wg*2 + i; int m = t >> 2, n = t & 3;
      int row0 = m*16 + (lane >> 4)*4;
      int pcol = n*16 + (lane & 15);
      f32x4 acc;
      #pragma unroll
      for (int r = 0; r < 4; ++r) acc[r] = boutd[row0 + r];
      h8 b0 = *(const h8*)&qs[pcol][(lane >> 4)*8];
      h8 b1 = *(const h8*)&qs[pcol][32 + (lane >> 4)*8];
      h8 b2 = *(const h8*)&xs[pcol][(lane >> 4)*8];
      h8 b3 = *(const h8*)&xs[pcol][32 + (lane >> 4)*8];
      acc = __builtin_amdgcn_mfma_f32_16x16x32_f16(A6[(m*4+0)*64 + lane], b0, acc, 0, 0, 0);
      acc = __builtin_amdgcn_mfma_f32_16x16x32_f16(A6[(m*4+1)*64 + lane], b1, acc, 0, 0, 0);
      acc = __builtin_amdgcn_mfma_f32_16x16x32_f16(A6[(m*4+2)*64 + lane], b2, acc, 0, 0, 0);
      acc = __builtin_amdgcn_mfma_f32_16x16x32_f16(A6[(m*4+3)*64 + lane], b3, acc, 0, 0, 0);
      #pragma unroll
      for (int r = 0; r < 4; ++r) ob[(row0 + r)*HW + pcol] = acc[r];
    }
  }
}

extern "C" void kernel_launch(void* const* d_in, const int* in_sizes, int n_in,
                              void* d_out, int out_size, void* d_ws, size_t ws_size,
                              hipStream_t stream)
{
  const float* x    = (const float*)d_in[0];
  const float* alpha= (const float*)d_in[1];
  const float* offw = (const float*)d_in[2];
  const float* offb = (const float*)d_in[3];
  const float* q_dw = (const float*)d_in[4];
  const float* q_pw = (const float*)d_in[5];
  const float* q_pb = (const float*)d_in[6];
  const float* k_dw = (const float*)d_in[7];
  const float* k_pw = (const float*)d_in[8];
  const float* v_dw = (const float*)d_in[10];
  const float* v_pw = (const float*)d_in[11];
  const float* v_pb = (const float*)d_in[12];
  const float* o_dw = (const float*)d_in[13];
  const float* o_pw = (const float*)d_in[14];
  const float* o_pb = (const float*)d_in[15];
  float* out = (float*)d_out;

  char* ws        = (char*)d_ws;
  _Float16* xt    = (_Float16*)ws;                          // 8,388,608 B
  _Float16* Apack2= (_Float16*)(ws + (size_t)4*HW*64*2);    // 12288 B
  _Float16* Apack6= Apack2 + 6144;                          // 16384 B
  float* bias96   = (float*)(Apack6 + 8192);
  float* boutd    = bias96 + 96;

  prep_kernel<<<1081, 256, 0, stream>>>(x, xt, alpha, q_dw, q_pw, q_pb, k_dw, k_pw,
                                        offw, offb, v_dw, v_pw, v_pb,
                                        o_dw, o_pw, o_pb,
                                        Apack2, Apack6, bias96, boutd);
  dam_kernel<<<1024, 512, 0, stream>>>(x, xt, Apack2, Apack6, bias96, boutd, out);
}

// Round 7
// 30.649 us; speedup vs baseline: 6.2144x; 1.6346x over previous
//
#include <hip/hip_runtime.h>

#define HW (128*128)
#define CHW (64*HW)

typedef _Float16 h2 __attribute__((ext_vector_type(2)));
typedef _Float16 h4 __attribute__((ext_vector_type(4)));
typedef _Float16 h8 __attribute__((ext_vector_type(8)));
typedef float f32x4 __attribute__((ext_vector_type(4)));

union H8P { h8 v; h2 p[4]; };
union H4P { h4 v; h2 p[2]; int2 i; };

#if !__has_builtin(__builtin_amdgcn_fdot2)
__device__ __forceinline__ float __builtin_amdgcn_fdot2(h2 a, h2 b, float c, bool) {
  return c + (float)a[0]*(float)b[0] + (float)a[1]*(float)b[1];
}
#endif

// ---------------- transpose + setup fused ----------------
__global__ __launch_bounds__(256) void prep_kernel(
    const float* __restrict__ x, _Float16* __restrict__ xt,
    const float* __restrict__ alpha,
    const float* __restrict__ q_dw, const float* __restrict__ q_pw, const float* __restrict__ q_pb,
    const float* __restrict__ k_dw, const float* __restrict__ k_pw,
    const float* __restrict__ offw, const float* __restrict__ offb,
    const float* __restrict__ v_dw, const float* __restrict__ v_pw, const float* __restrict__ v_pb,
    const float* __restrict__ o_dw, const float* __restrict__ o_pw, const float* __restrict__ o_pb,
    _Float16* __restrict__ Apack2, _Float16* __restrict__ Apack6,
    float* __restrict__ bias96, float* __restrict__ boutd)
{
  int tid = threadIdx.x;
  if (blockIdx.x < 1024) {
    __shared__ float t[64][65];
    int i0 = blockIdx.x;
    int blk = (i0 & 7)*128 + (i0 >> 3);
    int b = blk >> 8; int y = (blk >> 1) & 127; int x0 = (blk & 1) << 6;
    int p = tid & 63, cq = tid >> 6;
    const float* xb = x + b*CHW + y*128 + x0;
    #pragma unroll
    for (int i = 0; i < 16; ++i) {
      int c = i*4 + cq;
      t[c][p] = xb[c*HW + p];
    }
    __syncthreads();
    int cpair = tid & 31, pq = tid >> 5;
    h2* xtb = (h2*)(xt + (size_t)(b*HW + y*128 + x0)*64);
    #pragma unroll
    for (int i = 0; i < 8; ++i) {
      int pp = i*8 + pq;
      h2 v; v[0] = (_Float16)t[cpair*2][pp]; v[1] = (_Float16)t[cpair*2+1][pp];
      xtb[pp*32 + cpair] = v;
    }
    return;
  }
  int bb = blockIdx.x - 1024;
  float a = alpha[0];
  if (bb < 24) {                       // Apack2: [6 mt][2 kt][64 lane][8]
    int e = bb*256 + tid;
    int j = e & 7, l = (e >> 3) & 63, kt = (e >> 9) & 1, mt = e >> 10;
    int row = mt*16 + (l & 15);
    int c   = kt*32 + (l >> 4)*8 + j;
    float v = 0.f;
    if (row < 64) {
      float s = 0.f;
      for (int o = 0; o < 64; ++o) s += k_pw[o*64+row]*q_pw[o*64+c];
      v = k_dw[row]*q_dw[c]*s;
    } else if (row < 82) {
      v = offw[(row-64)*64 + c];
    }
    Apack2[e] = (_Float16)v;
  } else if (bb < 56) {                // Apack6: [4 mt][4 kt][64 lane][8]
    int e = (bb-24)*256 + tid;
    int j = e & 7, l = (e >> 3) & 63, kt = (e >> 9) & 3, mt = e >> 11;
    int o  = mt*16 + (l & 15);
    int cc = kt*32 + (l >> 4)*8 + j;
    float v;
    if (cc < 64) {
      float s = 0.f;
      for (int h = 0; h < 64; ++h) s += o_pw[o*64+h]*o_dw[h]*v_pw[h*64+cc];
      v = a*v_dw[cc]*s;
    } else {
      int c2 = cc - 64;
      float s = 0.f;
      for (int h = 0; h < 64; ++h) s += o_pw[o*64+h]*o_dw[h]*q_pw[h*64+c2];
      v = q_dw[c2]*s;
    }
    Apack6[e] = (_Float16)v;
  } else {
    if (tid < 96) {
      float v = 0.f;
      if (tid < 64) {
        float s = 0.f;
        for (int o = 0; o < 64; ++o) s += k_pw[o*64+tid]*q_pb[o];
        v = k_dw[tid]*s;
      } else if (tid < 82) {
        v = offb[tid-64];
      }
      bias96[tid] = v;
    } else if (tid >= 128 && tid < 192) {
      int o = tid - 128;
      float s2 = 0.f;
      for (int h = 0; h < 64; ++h) s2 += o_pw[o*64+h]*o_dw[h]*(a*v_pb[h]+q_pb[h]);
      boutd[o] = o_pb[o] + s2;
    }
  }
}

// ---------------- fused main kernel: 64 px/block, 512 threads ------------------
// LDS (32256 B):
//  A [0,9216):      xs f16 [64][72]                       live P1..P6
//  B [9216,18432):  qkL f16 [64][72] (P2..P3) | qs (P5..P6)
//  C [18432,23040): offsF f32 [18][64]  (P2..P2.5)
//  D [23040,32256): prm int4[576]       (P2.5..P3)
__global__ __launch_bounds__(512, 6) void dam_kernel(
  const float* __restrict__ x, const _Float16* __restrict__ xt,
  const _Float16* __restrict__ Apack2, const _Float16* __restrict__ Apack6,
  const float* __restrict__ bias96, const float* __restrict__ boutd,
  float* __restrict__ out)
{
  __shared__ __align__(16) char lds[32256];
  _Float16 (*xs)[72]  = (_Float16 (*)[72])lds;
  _Float16 (*qkL)[72] = (_Float16 (*)[72])(lds + 9216);
  _Float16 (*qs)[72]  = (_Float16 (*)[72])(lds + 9216);
  float (*offsF)[64]  = (float (*)[64])(lds + 18432);
  int4* prm           = (int4*)(lds + 23040);          // [576]

  int i0 = blockIdx.x;
  int blk = (i0 & 7)*128 + (i0 >> 3);      // XCD swizzle
  int b = blk >> 8; int y = (blk >> 1) & 127; int x0 = (blk & 1) << 6;
  int tid = threadIdx.x;
  int p = tid & 63;
  int g = tid >> 6;
  int wg = __builtin_amdgcn_readfirstlane(g);
  int lane = tid & 63;

  // ---- P1: stage x tile [p][c] f16 ; one b128 write per thread ----
  const float* xb = x + b*CHW + y*128 + x0;
  {
    h8 v;
    #pragma unroll
    for (int i = 0; i < 8; ++i) v[i] = (_Float16)xb[(wg*8 + i)*HW + p];
    *(h8*)&xs[p][wg*8] = v;
  }
  __syncthreads();

  // ---- P2: [qk | offsets] = A2 @ x_tile via MFMA. M=96, K=64, N=64 ----
  {
    const h8* A2 = (const h8*)Apack2;
    #pragma unroll
    for (int i = 0; i < 3; ++i) {
      int t = wg*3 + i; int m = t >> 2, n = t & 3;
      int row0 = m*16 + (lane >> 4)*4;
      int pcol = n*16 + (lane & 15);
      f32x4 acc;
      #pragma unroll
      for (int r = 0; r < 4; ++r) acc[r] = bias96[row0 + r];
      h8 b0 = *(const h8*)&xs[pcol][(lane >> 4)*8];
      h8 b1 = *(const h8*)&xs[pcol][32 + (lane >> 4)*8];
      acc = __builtin_amdgcn_mfma_f32_16x16x32_f16(A2[(m*2+0)*64 + lane], b0, acc, 0, 0, 0);
      acc = __builtin_amdgcn_mfma_f32_16x16x32_f16(A2[(m*2+1)*64 + lane], b1, acc, 0, 0, 0);
      if (m < 4) {
        h4 v;
        #pragma unroll
        for (int r = 0; r < 4; ++r) v[r] = (_Float16)acc[r];
        *(h4*)&qkL[pcol][m*16 + (lane >> 4)*4] = v;
      } else {
        #pragma unroll
        for (int r = 0; r < 4; ++r) {
          int row = row0 + r;
          if (row < 82) offsF[row - 64][pcol] = acc[r];
        }
      }
    }
  }
  __syncthreads();

  // ---- P2.5: per-(k,p) sampling params computed ONCE -> prm[576] ----
  #pragma unroll
  for (int pass = 0; pass < 2; ++pass) {
    int e = tid + pass*512;
    if (e < 576) {
      int k = e >> 6, pp = e & 63;
      float dx = offsF[k][pp];
      float dy = offsF[9+k][pp];
      float fx = (float)(x0 + pp);
      float fy = (float)y;
      float gx = 2.0f*(fx + dx)/127.0f - 1.0f;
      float gy = 2.0f*(fy + dy)/127.0f - 1.0f;
      float ix = ((gx + 1.0f)*128.0f - 1.0f)*0.5f;
      float iy = ((gy + 1.0f)*128.0f - 1.0f)*0.5f;
      float x0f = floorf(ix), y0f = floorf(iy);
      float wx = ix - x0f, wy = iy - y0f;
      int xi = (int)x0f, yi = (int)y0f;
      bool vx0 = (xi >= 0) && (xi < 128);
      bool vx1 = (xi >= -1) && (xi < 127);
      bool vy0 = (yi >= 0) && (yi < 128);
      bool vy1 = (yi >= -1) && (yi < 127);
      H4P w;
      w.v[0] = (_Float16)((1.f-wy)*(1.f-wx)*((vy0&&vx0)?1.f:0.f));
      w.v[1] = (_Float16)((1.f-wy)*wx      *((vy0&&vx1)?1.f:0.f));
      w.v[2] = (_Float16)(wy*(1.f-wx)      *((vy1&&vx0)?1.f:0.f));
      w.v[3] = (_Float16)(wy*wx            *((vy1&&vx1)?1.f:0.f));
      int xc0 = min(max(xi,0),127), xc1 = min(max(xi+1,0),127);
      int yc0 = min(max(yi,0),127), yc1 = min(max(yi+1,0),127);
      int4 pr;
      pr.x = (yc0*128 + xc0)*64;
      pr.y = (xc1 - xc0)*64 | (((yc1 - yc0)*8192) << 16);
      pr.z = w.i.x;
      pr.w = w.i.y;
      prm[e] = pr;
    }
  }
  // hoist qk chunk for the NEW lane mapping: pixel pxl, channel chunk ch8
  int pxl = wg*8 + (lane >> 3);
  int ch8 = (lane & 7)*8;
  H8P qkh; qkh.v = *(const h8*)&qkL[pxl][ch8];
  __syncthreads();      // prm ready

  const _Float16* xtb = xt + (size_t)b*HW*64 + ch8;

  // ---- P3: sampling. Lane owns (pixel pxl, channels ch8..ch8+7). ----
  // 8 consecutive lanes read one contiguous 128B channel row per corner.
  h2 smp[9][4];
  float sarr[9];
  #pragma unroll
  for (int k = 0; k < 9; ++k) {
    int4 pr = prm[k*64 + pxl];
    H4P w; w.i.x = pr.z; w.i.y = pr.w;
    int dxs = pr.y & 0xFFFF;
    int dys = pr.y >> 16;
    const _Float16* base = xtb + pr.x;
    H8P A, Bc, Cc, D;
    A.v  = *(const h8*)(base);
    Bc.v = *(const h8*)(base + dxs);
    Cc.v = *(const h8*)(base + dys);
    D.v  = *(const h8*)(base + dys + dxs);
    h2 w0h; w0h[0] = w.v[0]; w0h[1] = w.v[0];
    h2 w1h; w1h[0] = w.v[1]; w1h[1] = w.v[1];
    h2 w2h; w2h[0] = w.v[2]; w2h[1] = w.v[2];
    h2 w3h; w3h[0] = w.v[3]; w3h[1] = w.v[3];
    float s = 0.f;
    #pragma unroll
    for (int j = 0; j < 4; ++j) {
      h2 v = A.p[j]*w0h + Bc.p[j]*w1h + Cc.p[j]*w2h + D.p[j]*w3h;
      smp[k][j] = v;
      s = __builtin_amdgcn_fdot2(v, qkh.p[j], s, false);
    }
    // reduce over the 8 chunk-lanes of this pixel
    s += __shfl_xor(s, 1, 64);
    s += __shfl_xor(s, 2, 64);
    s += __shfl_xor(s, 4, 64);
    sarr[k] = s;
  }

  // ---- P4: softmax over k, fully register-local (all lanes of a pixel identical) ----
  float m = sarr[0];
  #pragma unroll
  for (int k = 1; k < 9; ++k) m = fmaxf(m, sarr[k]);
  float ssum = 0.f;
  #pragma unroll
  for (int k = 0; k < 9; ++k) { float e2 = __expf(sarr[k]-m); ssum += e2; sarr[k] = e2; }
  float inv = 1.f/ssum;

  // ---- P5: S = sum_k attn_k * smp_k (registers) ----
  h2 S2[4];
  #pragma unroll
  for (int j = 0; j < 4; ++j) { S2[j][0] = (_Float16)0.f; S2[j][1] = (_Float16)0.f; }
  #pragma unroll
  for (int k = 0; k < 9; ++k) {
    _Float16 akh = (_Float16)(sarr[k]*inv);
    h2 ak; ak[0] = akh; ak[1] = akh;
    #pragma unroll
    for (int j = 0; j < 4; ++j) S2[j] = S2[j] + ak*smp[k][j];
  }
  __syncthreads();      // all waves done reading qkL/prm; safe to overwrite with qs
  {
    H8P sv;
    sv.p[0] = S2[0]; sv.p[1] = S2[1]; sv.p[2] = S2[2]; sv.p[3] = S2[3];
    *(h8*)&qs[pxl][ch8] = sv.v;
  }
  __syncthreads();

  // ---- P6: out = A6 @ [S; x] + bout via MFMA. M=64, K=128, N=64 ----
  {
    const h8* A6 = (const h8*)Apack6;
    float* ob = out + b*CHW + y*128 + x0;
    #pragma unroll
    for (int i = 0; i < 2; ++i) {
      int t = wg*2 + i; int m2 = t >> 2, n = t & 3;
      int row0 = m2*16 + (lane >> 4)*4;
      int pcol = n*16 + (lane & 15);
      f32x4 acc;
      #pragma unroll
      for (int r = 0; r < 4; ++r) acc[r] = boutd[row0 + r];
      h8 b0 = *(const h8*)&qs[pcol][(lane >> 4)*8];
      h8 b1 = *(const h8*)&qs[pcol][32 + (lane >> 4)*8];
      h8 b2 = *(const h8*)&xs[pcol][(lane >> 4)*8];
      h8 b3 = *(const h8*)&xs[pcol][32 + (lane >> 4)*8];
      acc = __builtin_amdgcn_mfma_f32_16x16x32_f16(A6[(m2*4+0)*64 + lane], b0, acc, 0, 0, 0);
      acc = __builtin_amdgcn_mfma_f32_16x16x32_f16(A6[(m2*4+1)*64 + lane], b1, acc, 0, 0, 0);
      acc = __builtin_amdgcn_mfma_f32_16x16x32_f16(A6[(m2*4+2)*64 + lane], b2, acc, 0, 0, 0);
      acc = __builtin_amdgcn_mfma_f32_16x16x32_f16(A6[(m2*4+3)*64 + lane], b3, acc, 0, 0, 0);
      #pragma unroll
      for (int r = 0; r < 4; ++r) ob[(row0 + r)*HW + pcol] = acc[r];
    }
  }
}

extern "C" void kernel_launch(void* const* d_in, const int* in_sizes, int n_in,
                              void* d_out, int out_size, void* d_ws, size_t ws_size,
                              hipStream_t stream)
{
  const float* x    = (const float*)d_in[0];
  const float* alpha= (const float*)d_in[1];
  const float* offw = (const float*)d_in[2];
  const float* offb = (const float*)d_in[3];
  const float* q_dw = (const float*)d_in[4];
  const float* q_pw = (const float*)d_in[5];
  const float* q_pb = (const float*)d_in[6];
  const float* k_dw = (const float*)d_in[7];
  const float* k_pw = (const float*)d_in[8];
  const float* v_dw = (const float*)d_in[10];
  const float* v_pw = (const float*)d_in[11];
  const float* v_pb = (const float*)d_in[12];
  const float* o_dw = (const float*)d_in[13];
  const float* o_pw = (const float*)d_in[14];
  const float* o_pb = (const float*)d_in[15];
  float* out = (float*)d_out;

  char* ws        = (char*)d_ws;
  _Float16* xt    = (_Float16*)ws;                          // 8,388,608 B
  _Float16* Apack2= (_Float16*)(ws + (size_t)4*HW*64*2);    // 12288 B
  _Float16* Apack6= Apack2 + 6144;                          // 16384 B
  float* bias96   = (float*)(Apack6 + 8192);
  float* boutd    = bias96 + 96;

  prep_kernel<<<1081, 256, 0, stream>>>(x, xt, alpha, q_dw, q_pw, q_pb, k_dw, k_pw,
                                        offw, offb, v_dw, v_pw, v_pb,
                                        o_dw, o_pw, o_pb,
                                        Apack2, Apack6, bias96, boutd);
  dam_kernel<<<1024, 512, 0, stream>>>(x, xt, Apack2, Apack6, bias96, boutd, out);
}

// Round 8
// 29.040 us; speedup vs baseline: 6.5587x; 1.0554x over previous
//
#include <hip/hip_runtime.h>

#define HW (128*128)
#define CHW (64*HW)

typedef _Float16 h2 __attribute__((ext_vector_type(2)));
typedef _Float16 h4 __attribute__((ext_vector_type(4)));
typedef _Float16 h8 __attribute__((ext_vector_type(8)));
typedef float f32x4 __attribute__((ext_vector_type(4)));

union H8P { h8 v; h2 p[4]; };
union H4P { h4 v; h2 p[2]; int2 i; };

#if !__has_builtin(__builtin_amdgcn_fdot2)
__device__ __forceinline__ float __builtin_amdgcn_fdot2(h2 a, h2 b, float c, bool) {
  return c + (float)a[0]*(float)b[0] + (float)a[1]*(float)b[1];
}
#endif

// ---------------- transpose + setup fused ----------------
__global__ __launch_bounds__(256) void prep_kernel(
    const float* __restrict__ x, _Float16* __restrict__ xt,
    const float* __restrict__ alpha,
    const float* __restrict__ q_dw, const float* __restrict__ q_pw, const float* __restrict__ q_pb,
    const float* __restrict__ k_dw, const float* __restrict__ k_pw,
    const float* __restrict__ offw, const float* __restrict__ offb,
    const float* __restrict__ v_dw, const float* __restrict__ v_pw, const float* __restrict__ v_pb,
    const float* __restrict__ o_dw, const float* __restrict__ o_pw, const float* __restrict__ o_pb,
    _Float16* __restrict__ Apack2, _Float16* __restrict__ Apack6,
    float* __restrict__ bias96, float* __restrict__ boutd)
{
  int tid = threadIdx.x;
  if (blockIdx.x < 1024) {
    __shared__ float t[64][65];
    int i0 = blockIdx.x;
    int blk = (i0 & 7)*128 + (i0 >> 3);
    int b = blk >> 8; int y = (blk >> 1) & 127; int x0 = (blk & 1) << 6;
    int p = tid & 63, cq = tid >> 6;
    const float* xb = x + b*CHW + y*128 + x0;
    #pragma unroll
    for (int i = 0; i < 16; ++i) {
      int c = i*4 + cq;
      t[c][p] = xb[c*HW + p];
    }
    __syncthreads();
    int cpair = tid & 31, pq = tid >> 5;
    h2* xtb = (h2*)(xt + (size_t)(b*HW + y*128 + x0)*64);
    #pragma unroll
    for (int i = 0; i < 8; ++i) {
      int pp = i*8 + pq;
      h2 v; v[0] = (_Float16)t[cpair*2][pp]; v[1] = (_Float16)t[cpair*2+1][pp];
      xtb[pp*32 + cpair] = v;
    }
    return;
  }
  int bb = blockIdx.x - 1024;
  float a = alpha[0];
  if (bb < 24) {                       // Apack2: [6 mt][2 kt][64 lane][8]
    int e = bb*256 + tid;
    int j = e & 7, l = (e >> 3) & 63, kt = (e >> 9) & 1, mt = e >> 10;
    int row = mt*16 + (l & 15);
    int c   = kt*32 + (l >> 4)*8 + j;
    float v = 0.f;
    if (row < 64) {
      float s = 0.f;
      for (int o = 0; o < 64; ++o) s += k_pw[o*64+row]*q_pw[o*64+c];
      v = k_dw[row]*q_dw[c]*s;
    } else if (row < 82) {
      v = offw[(row-64)*64 + c];
    }
    Apack2[e] = (_Float16)v;
  } else if (bb < 56) {                // Apack6: [4 mt][4 kt][64 lane][8]
    int e = (bb-24)*256 + tid;
    int j = e & 7, l = (e >> 3) & 63, kt = (e >> 9) & 3, mt = e >> 11;
    int o  = mt*16 + (l & 15);
    int cc = kt*32 + (l >> 4)*8 + j;
    float v;
    if (cc < 64) {
      float s = 0.f;
      for (int h = 0; h < 64; ++h) s += o_pw[o*64+h]*o_dw[h]*v_pw[h*64+cc];
      v = a*v_dw[cc]*s;
    } else {
      int c2 = cc - 64;
      float s = 0.f;
      for (int h = 0; h < 64; ++h) s += o_pw[o*64+h]*o_dw[h]*q_pw[h*64+c2];
      v = q_dw[c2]*s;
    }
    Apack6[e] = (_Float16)v;
  } else {
    if (tid < 96) {
      float v = 0.f;
      if (tid < 64) {
        float s = 0.f;
        for (int o = 0; o < 64; ++o) s += k_pw[o*64+tid]*q_pb[o];
        v = k_dw[tid]*s;
      } else if (tid < 82) {
        v = offb[tid-64];
      }
      bias96[tid] = v;
    } else if (tid >= 128 && tid < 192) {
      int o = tid - 128;
      float s2 = 0.f;
      for (int h = 0; h < 64; ++h) s2 += o_pw[o*64+h]*o_dw[h]*(a*v_pb[h]+q_pb[h]);
      boutd[o] = o_pb[o] + s2;
    }
  }
}

// ---------------- fused main kernel: 64 px/block, 512 threads ------------------
// LDS (32256 B):
//  A [0,9216):      xs f16 [64][72]                       live P1..P6
//  B [9216,18432):  qkL f16 [64][72] (P2..P3) | qs (P5..P6)
//  C [18432,23040): offsF f32 [18][64]  (P2..P2.5)
//  D [23040,32256): prm int4[576]       (P2.5..P3)
__global__ __launch_bounds__(512, 4) void dam_kernel(
  const _Float16* __restrict__ xt,
  const _Float16* __restrict__ Apack2, const _Float16* __restrict__ Apack6,
  const float* __restrict__ bias96, const float* __restrict__ boutd,
  float* __restrict__ out)
{
  __shared__ __align__(16) char lds[32256];
  _Float16 (*xs)[72]  = (_Float16 (*)[72])lds;
  _Float16 (*qkL)[72] = (_Float16 (*)[72])(lds + 9216);
  _Float16 (*qs)[72]  = (_Float16 (*)[72])(lds + 9216);
  float (*offsF)[64]  = (float (*)[64])(lds + 18432);
  int4* prm           = (int4*)(lds + 23040);          // [576]

  int i0 = blockIdx.x;
  int blk = (i0 & 7)*128 + (i0 >> 3);      // XCD swizzle
  int b = blk >> 8; int y = (blk >> 1) & 127; int x0 = (blk & 1) << 6;
  int tid = threadIdx.x;
  int g = tid >> 6;
  int wg = __builtin_amdgcn_readfirstlane(g);
  int lane = tid & 63;

  // ---- P1: stage x tile [p][c] f16 straight from xt (contiguous 8 KB) ----
  {
    const h8* src = (const h8*)(xt + (size_t)(b*HW + y*128 + x0)*64);
    h8 v = src[tid];
    *(h8*)&xs[tid >> 3][(tid & 7)*8] = v;
  }
  __syncthreads();

  // ---- P2: [qk | offsets] = A2 @ x_tile via MFMA. M=96, K=64, N=64 ----
  {
    const h8* A2 = (const h8*)Apack2;
    #pragma unroll
    for (int i = 0; i < 3; ++i) {
      int t = wg*3 + i; int m = t >> 2, n = t & 3;
      int row0 = m*16 + (lane >> 4)*4;
      int pcol = n*16 + (lane & 15);
      f32x4 acc;
      #pragma unroll
      for (int r = 0; r < 4; ++r) acc[r] = bias96[row0 + r];
      h8 b0 = *(const h8*)&xs[pcol][(lane >> 4)*8];
      h8 b1 = *(const h8*)&xs[pcol][32 + (lane >> 4)*8];
      acc = __builtin_amdgcn_mfma_f32_16x16x32_f16(A2[(m*2+0)*64 + lane], b0, acc, 0, 0, 0);
      acc = __builtin_amdgcn_mfma_f32_16x16x32_f16(A2[(m*2+1)*64 + lane], b1, acc, 0, 0, 0);
      if (m < 4) {
        h4 v;
        #pragma unroll
        for (int r = 0; r < 4; ++r) v[r] = (_Float16)acc[r];
        *(h4*)&qkL[pcol][m*16 + (lane >> 4)*4] = v;
      } else {
        #pragma unroll
        for (int r = 0; r < 4; ++r) {
          int row = row0 + r;
          if (row < 82) offsF[row - 64][pcol] = acc[r];
        }
      }
    }
  }
  __syncthreads();

  // ---- P2.5: per-(k,p) sampling params computed ONCE -> prm[576] ----
  #pragma unroll
  for (int pass = 0; pass < 2; ++pass) {
    int e = tid + pass*512;
    if (e < 576) {
      int k = e >> 6, pp = e & 63;
      float dx = offsF[k][pp];
      float dy = offsF[9+k][pp];
      float fx = (float)(x0 + pp);
      float fy = (float)y;
      float gx = 2.0f*(fx + dx)/127.0f - 1.0f;
      float gy = 2.0f*(fy + dy)/127.0f - 1.0f;
      float ix = ((gx + 1.0f)*128.0f - 1.0f)*0.5f;
      float iy = ((gy + 1.0f)*128.0f - 1.0f)*0.5f;
      float x0f = floorf(ix), y0f = floorf(iy);
      float wx = ix - x0f, wy = iy - y0f;
      int xi = (int)x0f, yi = (int)y0f;
      bool vx0 = (xi >= 0) && (xi < 128);
      bool vx1 = (xi >= -1) && (xi < 127);
      bool vy0 = (yi >= 0) && (yi < 128);
      bool vy1 = (yi >= -1) && (yi < 127);
      H4P w;
      w.v[0] = (_Float16)((1.f-wy)*(1.f-wx)*((vy0&&vx0)?1.f:0.f));
      w.v[1] = (_Float16)((1.f-wy)*wx      *((vy0&&vx1)?1.f:0.f));
      w.v[2] = (_Float16)(wy*(1.f-wx)      *((vy1&&vx0)?1.f:0.f));
      w.v[3] = (_Float16)(wy*wx            *((vy1&&vx1)?1.f:0.f));
      int xc0 = min(max(xi,0),127), xc1 = min(max(xi+1,0),127);
      int yc0 = min(max(yi,0),127), yc1 = min(max(yi+1,0),127);
      int4 pr;
      pr.x = (yc0*128 + xc0)*64;
      pr.y = (xc1 - xc0)*64 | (((yc1 - yc0)*8192) << 16);
      pr.z = w.i.x;
      pr.w = w.i.y;
      prm[e] = pr;
    }
  }
  // lane mapping for P3: pixel pxl, channel chunk ch8
  int pxl = wg*8 + (lane >> 3);
  int ch8 = (lane & 7)*8;
  H8P qkh; qkh.v = *(const h8*)&qkL[pxl][ch8];
  __syncthreads();      // prm ready

  const _Float16* xtb = xt + (size_t)b*HW*64 + ch8;

  // ---- P3: sampling, 3-k batches (12 corner loads in flight per batch). ----
  // 8 consecutive lanes read one contiguous 128B channel row per corner.
  h2 smp[9][4];
  float sarr[9];
  #pragma unroll
  for (int kb = 0; kb < 3; ++kb) {
    int4 pr[3];
    #pragma unroll
    for (int u = 0; u < 3; ++u) pr[u] = prm[(kb*3+u)*64 + pxl];
    H8P A[3], Bc[3], Cc[3], D[3];
    #pragma unroll
    for (int u = 0; u < 3; ++u) {
      int dxs = pr[u].y & 0xFFFF;
      int dys = pr[u].y >> 16;
      const _Float16* base = xtb + pr[u].x;
      A[u].v  = *(const h8*)(base);
      Bc[u].v = *(const h8*)(base + dxs);
      Cc[u].v = *(const h8*)(base + dys);
      D[u].v  = *(const h8*)(base + dys + dxs);
    }
    #pragma unroll
    for (int u = 0; u < 3; ++u) {
      int k = kb*3 + u;
      H4P w; w.i.x = pr[u].z; w.i.y = pr[u].w;
      h2 w0h; w0h[0] = w.v[0]; w0h[1] = w.v[0];
      h2 w1h; w1h[0] = w.v[1]; w1h[1] = w.v[1];
      h2 w2h; w2h[0] = w.v[2]; w2h[1] = w.v[2];
      h2 w3h; w3h[0] = w.v[3]; w3h[1] = w.v[3];
      float s = 0.f;
      #pragma unroll
      for (int j = 0; j < 4; ++j) {
        h2 v = A[u].p[j]*w0h + Bc[u].p[j]*w1h + Cc[u].p[j]*w2h + D[u].p[j]*w3h;
        smp[k][j] = v;
        s = __builtin_amdgcn_fdot2(v, qkh.p[j], s, false);
      }
      s += __shfl_xor(s, 1, 64);
      s += __shfl_xor(s, 2, 64);
      s += __shfl_xor(s, 4, 64);
      sarr[k] = s;
    }
  }

  // ---- P4: softmax over k, fully register-local ----
  float m = sarr[0];
  #pragma unroll
  for (int k = 1; k < 9; ++k) m = fmaxf(m, sarr[k]);
  float ssum = 0.f;
  #pragma unroll
  for (int k = 0; k < 9; ++k) { float e2 = __expf(sarr[k]-m); ssum += e2; sarr[k] = e2; }
  float inv = 1.f/ssum;

  // ---- P5: S = sum_k attn_k * smp_k (registers) ----
  h2 S2[4];
  #pragma unroll
  for (int j = 0; j < 4; ++j) { S2[j][0] = (_Float16)0.f; S2[j][1] = (_Float16)0.f; }
  #pragma unroll
  for (int k = 0; k < 9; ++k) {
    _Float16 akh = (_Float16)(sarr[k]*inv);
    h2 ak; ak[0] = akh; ak[1] = akh;
    #pragma unroll
    for (int j = 0; j < 4; ++j) S2[j] = S2[j] + ak*smp[k][j];
  }
  __syncthreads();      // all waves done reading qkL/prm; safe to overwrite with qs
  {
    H8P sv;
    sv.p[0] = S2[0]; sv.p[1] = S2[1]; sv.p[2] = S2[2]; sv.p[3] = S2[3];
    *(h8*)&qs[pxl][ch8] = sv.v;
  }
  __syncthreads();

  // ---- P6: out = A6 @ [S; x] + bout via MFMA. M=64, K=128, N=64 ----
  {
    const h8* A6 = (const h8*)Apack6;
    float* ob = out + b*CHW + y*128 + x0;
    #pragma unroll
    for (int i = 0; i < 2; ++i) {
      int t = wg*2 + i; int m2 = t >> 2, n = t & 3;
      int row0 = m2*16 + (lane >> 4)*4;
      int pcol = n*16 + (lane & 15);
      f32x4 acc;
      #pragma unroll
      for (int r = 0; r < 4; ++r) acc[r] = boutd[row0 + r];
      h8 b0 = *(const h8*)&qs[pcol][(lane >> 4)*8];
      h8 b1 = *(const h8*)&qs[pcol][32 + (lane >> 4)*8];
      h8 b2 = *(const h8*)&xs[pcol][(lane >> 4)*8];
      h8 b3 = *(const h8*)&xs[pcol][32 + (lane >> 4)*8];
      acc = __builtin_amdgcn_mfma_f32_16x16x32_f16(A6[(m2*4+0)*64 + lane], b0, acc, 0, 0, 0);
      acc = __builtin_amdgcn_mfma_f32_16x16x32_f16(A6[(m2*4+1)*64 + lane], b1, acc, 0, 0, 0);
      acc = __builtin_amdgcn_mfma_f32_16x16x32_f16(A6[(m2*4+2)*64 + lane], b2, acc, 0, 0, 0);
      acc = __builtin_amdgcn_mfma_f32_16x16x32_f16(A6[(m2*4+3)*64 + lane], b3, acc, 0, 0, 0);
      #pragma unroll
      for (int r = 0; r < 4; ++r) ob[(row0 + r)*HW + pcol] = acc[r];
    }
  }
}

extern "C" void kernel_launch(void* const* d_in, const int* in_sizes, int n_in,
                              void* d_out, int out_size, void* d_ws, size_t ws_size,
                              hipStream_t stream)
{
  const float* x    = (const float*)d_in[0];
  const float* alpha= (const float*)d_in[1];
  const float* offw = (const float*)d_in[2];
  const float* offb = (const float*)d_in[3];
  const float* q_dw = (const float*)d_in[4];
  const float* q_pw = (const float*)d_in[5];
  const float* q_pb = (const float*)d_in[6];
  const float* k_dw = (const float*)d_in[7];
  const float* k_pw = (const float*)d_in[8];
  const float* v_dw = (const float*)d_in[10];
  const float* v_pw = (const float*)d_in[11];
  const float* v_pb = (const float*)d_in[12];
  const float* o_dw = (const float*)d_in[13];
  const float* o_pw = (const float*)d_in[14];
  const float* o_pb = (const float*)d_in[15];
  float* out = (float*)d_out;

  char* ws        = (char*)d_ws;
  _Float16* xt    = (_Float16*)ws;                          // 8,388,608 B
  _Float16* Apack2= (_Float16*)(ws + (size_t)4*HW*64*2);    // 12288 B
  _Float16* Apack6= Apack2 + 6144;                          // 16384 B
  float* bias96   = (float*)(Apack6 + 8192);
  float* boutd    = bias96 + 96;

  prep_kernel<<<1081, 256, 0, stream>>>(x, xt, alpha, q_dw, q_pw, q_pb, k_dw, k_pw,
                                        offw, offb, v_dw, v_pw, v_pb,
                                        o_dw, o_pw, o_pb,
                                        Apack2, Apack6, bias96, boutd);
  dam_kernel<<<1024, 512, 0, stream>>>(xt, Apack2, Apack6, bias96, boutd, out);
}